// Round 11
// baseline (246.205 us; speedup 1.0000x reference)
//
#include <hip/hip_runtime.h>

typedef __attribute__((ext_vector_type(8))) short bf16x8;
typedef __attribute__((ext_vector_type(4))) float f32x4;

#define DEV static __device__ __forceinline__

DEV unsigned short f2bf(float f){
  union { float f; unsigned u; } v; v.f = f;
  unsigned r = v.u + 0x7fffu + ((v.u >> 16) & 1u);
  return (unsigned short)(r >> 16);
}
DEV float bf2f(unsigned short u){
  union { unsigned u; float f; } v; v.u = ((unsigned)u) << 16;
  return v.f;
}
DEV unsigned long long pk4(float a, float b, float c, float d){
  unsigned lo = (unsigned)f2bf(a) | ((unsigned)f2bf(b) << 16);
  unsigned hi = (unsigned)f2bf(c) | ((unsigned)f2bf(d) << 16);
  return ((unsigned long long)hi << 32) | lo;
}

// =============== fused prep: weight transposes/converts + x prep + router ===============
__global__ __launch_bounds__(256) void k_prep(const float* __restrict__ x,
                                              const float* __restrict__ Wq,
                                              const float* __restrict__ Wr,
                                              const float* __restrict__ br,
                                              const float* __restrict__ Wk,
                                              const float* __restrict__ Wv,
                                              const float* __restrict__ Wo,
                                              const float* __restrict__ bias0,
                                              unsigned short* __restrict__ WkT,
                                              unsigned short* __restrict__ WvT,
                                              unsigned short* __restrict__ WoT,
                                              unsigned short* __restrict__ Wqb,
                                              unsigned short* __restrict__ xb,
                                              unsigned short* __restrict__ xT,
                                              float* __restrict__ routT){
  __shared__ float tile[32*33];
  __shared__ float lg[32][8];
  __shared__ float rt2[32][8];
  int bid = blockIdx.x;
  int t = threadIdx.x;
  int tx = t & 31, ty = t >> 5;

  if (bid < 8192){                      // Wk (0..4095) / Wv (4096..8191): [8][256][2048] -> [8][2048][256]
    const float* src = (bid < 4096) ? Wk : Wv;
    unsigned short* dst = (bid < 4096) ? WkT : WvT;
    int q = bid & 4095;
    int bat = q >> 9, rem = q & 511;
    int c0 = (rem >> 3) * 32, r0 = (rem & 7) * 32;
    size_t boff = (size_t)bat * 256 * 2048;
    for (int i = 0; i < 4; i++)
      tile[(ty + i*8)*33 + tx] = src[boff + (size_t)(r0 + ty + i*8) * 2048 + c0 + tx];
    __syncthreads();
    for (int i = 0; i < 4; i++)
      dst[boff + (size_t)(c0 + ty + i*8) * 256 + r0 + tx] = f2bf(tile[tx*33 + ty + i*8]);
  } else if (bid < 8704){               // Wo: [2048][256] -> [256][2048]
    int q = bid - 8192;
    int c0 = (q >> 6) * 32, r0 = (q & 63) * 32;
    for (int i = 0; i < 4; i++)
      tile[(ty + i*8)*33 + tx] = Wo[(size_t)(r0 + ty + i*8) * 256 + c0 + tx];
    __syncthreads();
    for (int i = 0; i < 4; i++)
      WoT[(size_t)(c0 + ty + i*8) * 2048 + r0 + tx] = f2bf(tile[tx*33 + ty + i*8]);
  } else if (bid < 8960){               // Wq plain convert [256][2048]
    int q = bid - 8704;
    size_t idx = (size_t)q * 2048 + t * 8;
    f32x4 a = *(const f32x4*)(Wq + idx);
    f32x4 b = *(const f32x4*)(Wq + idx + 4);
    *(unsigned long long*)(Wqb + idx)     = pk4(a[0], a[1], a[2], a[3]);
    *(unsigned long long*)(Wqb + idx + 4) = pk4(b[0], b[1], b[2], b[3]);
  } else if (bid < 9984){               // x: [2][2048][256] -> xb [4096][256] + xT [2][256][2048]
    int q = bid - 8960;
    int bat = q >> 9, rem = q & 511;
    int c0 = (rem >> 6) * 32, r0 = (rem & 63) * 32;
    size_t boff = (size_t)bat * 2048 * 256;
    for (int i = 0; i < 4; i++){
      float v = x[boff + (size_t)(r0 + ty + i*8) * 256 + c0 + tx];
      tile[(ty + i*8)*33 + tx] = v;
      xb[boff + (size_t)(r0 + ty + i*8) * 256 + c0 + tx] = f2bf(v);
    }
    __syncthreads();
    for (int i = 0; i < 4; i++)
      xT[(size_t)(bat*256 + c0 + ty + i*8) * 2048 + r0 + tx] = f2bf(tile[tx*33 + ty + i*8]);
  } else {                              // router: 128 blocks, 32 tokens each
    int row = t >> 3, mm = t & 7;
    int n = (bid - 9984) * 32 + row;
    const float* xr = x + (size_t)n * 256;
    float acc = 0.f;
    for (int d = 0; d < 256; d++) acc += xr[d] * Wr[d * 8 + mm];
    acc += br[mm];
    lg[row][mm] = acc;
    __syncthreads();
    if (t < 32){
      int r = t; int n2 = (bid - 9984) * 32 + r; int b = n2 >> 11;
      float mx = -1e30f;
      for (int i = 0; i < 8; i++) mx = fmaxf(mx, lg[r][i]);
      float s[8]; float sum = 0.f;
      for (int i = 0; i < 8; i++){ s[i] = __expf(lg[r][i] - mx); sum += s[i]; }
      for (int i = 0; i < 8; i++) s[i] /= sum;
      float bb[8];
      for (int i = 0; i < 8; i++) bb[i] = s[i] + bias0[b * 8 + i];
      int i1 = 0;
      for (int i = 1; i < 8; i++) if (bb[i] > bb[i1]) i1 = i;
      int i2 = -1;
      for (int i = 0; i < 8; i++){ if (i == i1) continue; if (i2 < 0 || bb[i] > bb[i2]) i2 = i; }
      float wsum = s[i1] + s[i2];
      for (int i = 0; i < 8; i++)
        rt2[r][i] = (i == i1) ? s[i1] / wsum : ((i == i2) ? s[i2] / wsum : 0.f);
    }
    __syncthreads();
    int n3 = (bid - 9984) * 32 + row;
    int b = n3 >> 11, sl = n3 & 2047;
    routT[((size_t)b * 8 + mm) * 2048 + sl] = rt2[row][mm];
  }
}

// =============== upart[bm*16+sc][d] = sum_{s in chunk} r*x ; rhop[bm*16+sc] (no atomics) ===============
__global__ __launch_bounds__(256) void k_usum(const unsigned short* __restrict__ xb,
                                              const float* __restrict__ routT,
                                              float* __restrict__ upart, float* __restrict__ rhop){
  __shared__ float rl[128];
  int bid = blockIdx.x;                 // 256 = bm(16) * sc(16)
  int sc = bid & 15, bm = bid >> 4, b = bm >> 3;
  int t = threadIdx.x;
  int s0 = sc * 128;
  if (t < 128) rl[t] = routT[(size_t)bm * 2048 + s0 + t];
  __syncthreads();
  float acc = 0.f;
  const unsigned short* xrow = xb + ((size_t)(b * 2048 + s0)) * 256 + t;
  for (int s = 0; s < 128; s++){
    float rv = rl[s];
    if (rv != 0.f)
      acc += rv * bf2f(xrow[(size_t)s * 256]);
  }
  upart[(size_t)bid * 256 + t] = acc;
  if (t == 0){
    float rs = 0.f;
    for (int s = 0; s < 128; s++) rs += rl[s];
    rhop[bid] = rs;
  }
}

// =============== ku/vu = WkT/WvT . u (u summed from partials in-block); rho emitted ===============
__global__ __launch_bounds__(256) void k_bias(const unsigned short* __restrict__ WkT,
                                              const unsigned short* __restrict__ WvT,
                                              const float* __restrict__ upart,
                                              const float* __restrict__ rhop,
                                              float* __restrict__ ku_g, float* __restrict__ vu_g,
                                              float* __restrict__ rho){
  __shared__ float uL[256];
  int bid = blockIdx.x, t = threadIdx.x;
  int bm = bid >> 3, hseg = bid & 7, m = bm & 7;
  {
    float s = 0.f;
    for (int scn = 0; scn < 16; scn++)
      s += upart[(size_t)(bm*16 + scn) * 256 + t];
    uL[t] = s;
  }
  if (hseg == 0 && t == 0){
    float rs = 0.f;
    for (int scn = 0; scn < 16; scn++) rs += rhop[bm*16 + scn];
    rho[bm] = rs;
  }
  __syncthreads();
  int hd = hseg * 256 + t;
  const unsigned short* wk = WkT + ((size_t)m*2048 + hd) * 256;
  const unsigned short* wv = WvT + ((size_t)m*2048 + hd) * 256;
  float sk = 0.f, sv = 0.f;
  for (int d8 = 0; d8 < 256; d8 += 8){
    bf16x8 a = *(const bf16x8*)(wk + d8);
    bf16x8 c = *(const bf16x8*)(wv + d8);
    for (int j = 0; j < 8; j++){
      sk += bf2f((unsigned short)a[j]) * uL[d8+j];
      sv += bf2f((unsigned short)c[j]) * uL[d8+j];
    }
  }
  ku_g[(size_t)bm*2048 + hd] = sk;
  vu_g[(size_t)bm*2048 + hd] = sv;
}

// =============== Gp[bm][kc] = X_chunk^T diag(r) X_chunk (256x256, K=256 tokens) ===============
__global__ __launch_bounds__(512) void k_gpart(const unsigned short* __restrict__ xT,
                                               const float* __restrict__ routT,
                                               unsigned short* __restrict__ Gp){
  __shared__ unsigned short As[256*72];     // scaled, 36 KB
  __shared__ unsigned short Bs[256*72];     // unscaled, 36 KB
  __shared__ float rl[64];
  int bid = blockIdx.x;                      // 128 = b(2) m(8) kc(8)
  int kc = bid & 7, m = (bid >> 3) & 7, b = bid >> 6;
  int bm = b * 8 + m;
  int t = threadIdx.x, lane = t & 63, w = t >> 6;
  int li = lane & 15, lgp = lane >> 4;
  int p = w >> 2, q = w & 3;
  f32x4 acc[8][4];
  for (int i = 0; i < 8; i++) for (int j = 0; j < 4; j++) acc[i][j] = (f32x4){0,0,0,0};
  for (int c4 = 0; c4 < 4; c4++){
    int s0 = kc * 256 + c4 * 64;
    if (t < 64) rl[t] = routT[(size_t)bm*2048 + s0 + t];
    __syncthreads();
    for (int qq = 0; qq < 4; qq++){
      int idx = t + qq*512;
      int row = idx >> 3, sc = (idx & 7) * 8;
      bf16x8 xv = *(const bf16x8*)(xT + ((size_t)(b*256 + row))*2048 + s0 + sc);
      *(bf16x8*)(&Bs[row*72 + sc]) = xv;
      f32x4 r0 = *(const f32x4*)(rl + sc);
      f32x4 r1 = *(const f32x4*)(rl + sc + 4);
      bf16x8 sv;
      sv[0]=(short)f2bf(bf2f((unsigned short)xv[0])*r0[0]);
      sv[1]=(short)f2bf(bf2f((unsigned short)xv[1])*r0[1]);
      sv[2]=(short)f2bf(bf2f((unsigned short)xv[2])*r0[2]);
      sv[3]=(short)f2bf(bf2f((unsigned short)xv[3])*r0[3]);
      sv[4]=(short)f2bf(bf2f((unsigned short)xv[4])*r1[0]);
      sv[5]=(short)f2bf(bf2f((unsigned short)xv[5])*r1[1]);
      sv[6]=(short)f2bf(bf2f((unsigned short)xv[6])*r1[2]);
      sv[7]=(short)f2bf(bf2f((unsigned short)xv[7])*r1[3]);
      *(bf16x8*)(&As[row*72 + sc]) = sv;
    }
    __syncthreads();
    for (int kk = 0; kk < 2; kk++){
      bf16x8 Bf[4];
      for (int j = 0; j < 4; j++)
        Bf[j] = *(const bf16x8*)(&Bs[(q*64 + j*16 + li)*72 + kk*32 + lgp*8]);
      for (int i = 0; i < 8; i++){
        bf16x8 Af = *(const bf16x8*)(&As[(p*128 + i*16 + li)*72 + kk*32 + lgp*8]);
        for (int j = 0; j < 4; j++)
          acc[i][j] = __builtin_amdgcn_mfma_f32_16x16x32_bf16(Af, Bf[j], acc[i][j], 0, 0, 0);
      }
    }
    __syncthreads();
  }
  // bounce C (col=d1 from A-pack, row=d2 from B-li) -> Gp[bm][kc][d2][d1]
  unsigned short* Cs = As;                   // 64 x 264 overlay
  for (int ph = 0; ph < 4; ph++){
    if (q == ph){
      for (int i = 0; i < 8; i++)
        for (int j = 0; j < 4; j++){
          int rr = j*16 + li, cc = p*128 + i*16 + lgp*4;
          *(unsigned long long*)(&Cs[rr*264 + cc]) =
            pk4(acc[i][j][0], acc[i][j][1], acc[i][j][2], acc[i][j][3]);
        }
    }
    __syncthreads();
    for (int qq = 0; qq < 4; qq++){
      int idx = t + qq*512;
      int row = idx >> 5, cc = (idx & 31) * 8;
      *(bf16x8*)(Gp + (((size_t)bm*8 + kc) << 16) + (size_t)(ph*64 + row)*256 + cc) =
        *(const bf16x8*)(&Cs[row*264 + cc]);
    }
    __syncthreads();
  }
}

// =============== reduce Gp over kc -> G[bm][256][256] ===============
__global__ __launch_bounds__(256) void k_gred(const unsigned short* __restrict__ Gp,
                                              unsigned short* __restrict__ G){
  int idx = blockIdx.x * 256 + threadIdx.x;
  int bm = idx >> 13; size_t e8 = (size_t)(idx & 8191) * 8;
  float s[8] = {0,0,0,0,0,0,0,0};
  for (int kc = 0; kc < 8; kc++){
    bf16x8 v = *(const bf16x8*)(Gp + (((size_t)bm*8 + kc) << 16) + e8);
    for (int j = 0; j < 8; j++) s[j] += bf2f((unsigned short)v[j]);
  }
  *(unsigned long long*)(G + ((size_t)bm << 16) + e8)     = pk4(s[0], s[1], s[2], s[3]);
  *(unsigned long long*)(G + ((size_t)bm << 16) + e8 + 4) = pk4(s[4], s[5], s[6], s[7]);
}

// =============== fused mem: memT[bh][vd][kd] = Sum_m Wk_mh^T G_bm Wv_mh + rank-1 ===============
// grid 128 = bh(16) x kq(8); per block kd-slice 32, full vd 256.
// stage1 (per m): Y[kd 32][d2 256] = Wk^T G  (Y in LDS)
// stage2 (per m): acc[kd][vd] += Y @ Wv   (f32 regs, accumulated over m)
__global__ __launch_bounds__(512) void k_mem2(const unsigned short* __restrict__ G,
                                              const unsigned short* __restrict__ WkT,
                                              const unsigned short* __restrict__ WvT,
                                              const float* __restrict__ bk,
                                              const float* __restrict__ bv,
                                              const float* __restrict__ ku_g,
                                              const float* __restrict__ vu_g,
                                              const float* __restrict__ rho,
                                              unsigned short* __restrict__ memT){
  __shared__ unsigned short Y[32*280];          // 17.5 KB, padded stride 280
  int lb = blockIdx.x;                           // 128
  int bid = (lb & 7) * 16 + (lb >> 3);           // bijective XCD swizzle (128 % 8 == 0)
  int kq = bid & 7, bh = bid >> 3;
  int b = bh >> 3, h = bh & 7;
  int hd0 = h * 256, kd0 = kq * 32;
  int t = threadIdx.x, lane = t & 63, w = t >> 6;
  int li = lane & 15, lgp = lane >> 4;

  f32x4 acc2[2][2];                              // [ai2: kd 16-block][bj: vd 16-block]
  for (int i = 0; i < 2; i++) for (int j = 0; j < 2; j++) acc2[i][j] = (f32x4){0,0,0,0};

  for (int m = 0; m < 8; m++){
    int bm = b * 8 + m;
    // ---- stage 1: Y[kd=li-side][d2=pack] ; wave w owns d2 slice w*32..w*32+32
    f32x4 a1[2][2];                              // [bi: kd][ai: d2]
    for (int i = 0; i < 2; i++) for (int j = 0; j < 2; j++) a1[i][j] = (f32x4){0,0,0,0};
    const unsigned short* gp  = G + ((size_t)bm << 16) + (size_t)(w*32 + li)*256 + lgp*8;
    const unsigned short* wkp = WkT + ((size_t)m*2048 + hd0 + kd0 + li)*256 + lgp*8;
    #pragma unroll
    for (int kk = 0; kk < 8; kk++){
      bf16x8 Ag[2], Bk[2];
      Ag[0] = *(const bf16x8*)(gp + kk*32);
      Ag[1] = *(const bf16x8*)(gp + 16*256 + kk*32);
      Bk[0] = *(const bf16x8*)(wkp + kk*32);
      Bk[1] = *(const bf16x8*)(wkp + 16*256 + kk*32);
      for (int bi = 0; bi < 2; bi++)
        for (int ai = 0; ai < 2; ai++)
          a1[bi][ai] = __builtin_amdgcn_mfma_f32_16x16x32_bf16(Ag[ai], Bk[bi], a1[bi][ai], 0, 0, 0);
    }
    for (int bi = 0; bi < 2; bi++)
      for (int ai = 0; ai < 2; ai++)
        *(unsigned long long*)(&Y[(bi*16 + li)*280 + w*32 + ai*16 + lgp*4]) =
          pk4(a1[bi][ai][0], a1[bi][ai][1], a1[bi][ai][2], a1[bi][ai][3]);
    __syncthreads();
    // ---- stage 2: acc2[kd=pack][vd=li-side] += Y @ Wv ; wave w owns vd slice w*32
    const unsigned short* wvp = WvT + ((size_t)m*2048 + hd0 + w*32 + li)*256 + lgp*8;
    #pragma unroll
    for (int kk = 0; kk < 8; kk++){
      bf16x8 Ay[2], Bv[2];
      Ay[0] = *(const bf16x8*)(&Y[(li)*280 + kk*32 + lgp*8]);
      Ay[1] = *(const bf16x8*)(&Y[(16 + li)*280 + kk*32 + lgp*8]);
      Bv[0] = *(const bf16x8*)(wvp + kk*32);
      Bv[1] = *(const bf16x8*)(wvp + 16*256 + kk*32);
      for (int ai2 = 0; ai2 < 2; ai2++)
        for (int bj = 0; bj < 2; bj++)
          acc2[ai2][bj] = __builtin_amdgcn_mfma_f32_16x16x32_bf16(Ay[ai2], Bv[bj], acc2[ai2][bj], 0, 0, 0);
    }
    __syncthreads();
  }
  // ---- rank-1 epilogue + direct store memT[vd][kd]
  float rhol[8];
  #pragma unroll
  for (int m = 0; m < 8; m++) rhol[m] = rho[b*8 + m];
  #pragma unroll
  for (int bj = 0; bj < 2; bj++){
    int vd = w*32 + bj*16 + li;
    int vdg = hd0 + vd;
    float bvv[8], bb[8];
    #pragma unroll
    for (int m = 0; m < 8; m++){
      bvv[m] = bv[(size_t)m*2048 + vdg];
      bb[m]  = vu_g[(size_t)(b*8+m)*2048 + vdg] + rhol[m]*bvv[m];
    }
    #pragma unroll
    for (int ai2 = 0; ai2 < 2; ai2++){
      int kd = kd0 + ai2*16 + lgp*4;
      int kdg = hd0 + kd;
      f32x4 s = acc2[ai2][bj];
      #pragma unroll
      for (int m = 0; m < 8; m++){
        f32x4 ku4 = *(const f32x4*)(ku_g + (size_t)(b*8+m)*2048 + kdg);
        f32x4 bk4 = *(const f32x4*)(bk + (size_t)m*2048 + kdg);
        s[0] += ku4[0]*bvv[m] + bk4[0]*bb[m];
        s[1] += ku4[1]*bvv[m] + bk4[1]*bb[m];
        s[2] += ku4[2]*bvv[m] + bk4[2]*bb[m];
        s[3] += ku4[3]*bvv[m] + bk4[3]*bb[m];
      }
      *(unsigned long long*)(memT + (size_t)bh*65536 + (size_t)vd*256 + kd) =
        pk4(s[0], s[1], s[2], s[3]);
    }
  }
}

// =============== E_h = Wq_h @ mem_h  -> Eb[b][d][h*256+vd]; qbAll = bq_h . mem_h ===============
__global__ __launch_bounds__(512) void k_emat(const unsigned short* __restrict__ memT,
                                              const unsigned short* __restrict__ Wqb,
                                              const float* __restrict__ bq,
                                              unsigned short* __restrict__ Eb,
                                              float* __restrict__ qbAll){
  __shared__ unsigned short Cs[16*264];
  int bid = blockIdx.x;                        // 64 = bh(16) * dseg(4)
  int dseg = bid & 3, bh = bid >> 2;
  int b = bh >> 3, h = bh & 7;
  int hd0 = h * 256, d0 = dseg * 64;
  int t = threadIdx.x, lane = t & 63, w = t >> 6;
  int li = lane & 15, lgp = lane >> 4;
  int r = w >> 2, c = w & 3;                   // r: vd half(128), c: d quarter(16)
  // out [vd 256][d 64]: A = memT rows vd, B = Wqb rows d (K = kd 256)
  f32x4 acc[8];
  for (int i = 0; i < 8; i++) acc[i] = (f32x4){0,0,0,0};
  for (int kk = 0; kk < 8; kk++){
    bf16x8 Bf = *(const bf16x8*)(Wqb + (size_t)(d0 + c*16 + li)*2048 + hd0 + kk*32 + lgp*8);
    for (int i = 0; i < 8; i++){
      bf16x8 Af = *(const bf16x8*)(memT + (size_t)bh*65536 + (size_t)(r*128 + i*16 + li)*256 + kk*32 + lgp*8);
      acc[i] = __builtin_amdgcn_mfma_f32_16x16x32_bf16(Af, Bf, acc[i], 0, 0, 0);
    }
  }
  // qb: qbAll[b][hd0+vd] = sum_kd bq[hd0+kd]*mem[kd][vd]
  if (dseg == 0 && t < 256){
    const unsigned short* mrow = memT + (size_t)bh*65536 + (size_t)t*256;
    float s = 0.f;
    for (int k8 = 0; k8 < 256; k8 += 8){
      bf16x8 v = *(const bf16x8*)(mrow + k8);
      for (int e = 0; e < 8; e++) s += bf2f((unsigned short)v[e]) * bq[hd0 + k8 + e];
    }
    qbAll[(size_t)b*2048 + hd0 + t] = s;
  }
  // bounce: C row=d (li of B), col=vd -> Eb[b][d][hd0+vd], 4 phases over c
  for (int ph = 0; ph < 4; ph++){
    if (c == ph){
      for (int i = 0; i < 8; i++)
        *(unsigned long long*)(&Cs[li*264 + r*128 + i*16 + lgp*4]) =
          pk4(acc[i][0], acc[i][1], acc[i][2], acc[i][3]);
    }
    __syncthreads();
    {
      int row = t >> 5, cc = (t & 31) * 8;     // 16 rows x 256 cols
      *(bf16x8*)(Eb + (size_t)b*524288 + (size_t)(d0 + ph*16 + row)*2048 + hd0 + cc) =
        *(const bf16x8*)(&Cs[row*264 + cc]);
    }
    __syncthreads();
  }
}

// =============== Fpart[ks][b][do][d] = Eb x Wo slice-K (split-K 8); tail: c0 wave-parallel ===============
__global__ __launch_bounds__(512) void k_fmat(const unsigned short* __restrict__ Eb,
                                              const unsigned short* __restrict__ WoT,
                                              const float* __restrict__ qbAll,
                                              const float* __restrict__ bo,
                                              float* __restrict__ Fpart,
                                              float* __restrict__ c0acc){
  __shared__ float qL[2048];
  int bid = blockIdx.x;
  int t = threadIdx.x;
  if (bid >= 256){                             // c0 blocks: bid 256,257 -> b (wave-parallel matvec)
    int b = bid - 256;
    for (int i = t; i < 2048; i += 512) qL[i] = qbAll[(size_t)b * 2048 + i];
    __syncthreads();
    int w = t >> 6, lane = t & 63;
    for (int dd = w; dd < 256; dd += 8){
      const unsigned short* wrow = WoT + (size_t)dd * 2048 + lane * 8;
      const float* qp = qL + lane * 8;
      float s = 0.f;
      for (int pass = 0; pass < 4; pass++){
        bf16x8 v = *(const bf16x8*)(wrow + pass * 512);
        const float* q = qp + pass * 512;
        for (int e = 0; e < 8; e++) s += bf2f((unsigned short)v[e]) * q[e];
      }
      for (int off = 32; off; off >>= 1) s += __shfl_down(s, off);
      if (lane == 0) c0acc[(size_t)b * 256 + dd] = s + bo[dd];
    }
    return;
  }
  // F blocks: 256 = b(2) x doseg(4) x dseg(4) x ks(8); 64x64 tile, K = 256
  int ks = bid & 7, dseg = (bid >> 3) & 3, doseg = (bid >> 5) & 3, b = bid >> 7;
  int do0 = doseg * 64, d0 = dseg * 64, k0 = ks * 256;
  int lane = t & 63, w = t >> 6;
  int li = lane & 15, lgp = lane >> 4;
  int r = w >> 2, c = w & 3;                   // r: do 2x32, c: d 4x16
  f32x4 acc[2];
  acc[0] = (f32x4){0,0,0,0}; acc[1] = (f32x4){0,0,0,0};
  const unsigned short* bp = Eb + (size_t)b*524288 + (size_t)(d0 + c*16 + li)*2048 + k0 + lgp*8;
  const unsigned short* ap = WoT + (size_t)(do0 + r*32 + li)*2048 + k0 + lgp*8;
  #pragma unroll
  for (int kk = 0; kk < 8; kk++){
    bf16x8 Bf = *(const bf16x8*)(bp + kk*32);
    bf16x8 Af0 = *(const bf16x8*)(ap + kk*32);
    bf16x8 Af1 = *(const bf16x8*)(ap + kk*32 + 16*2048);
    acc[0] = __builtin_amdgcn_mfma_f32_16x16x32_bf16(Af0, Bf, acc[0], 0, 0, 0);
    acc[1] = __builtin_amdgcn_mfma_f32_16x16x32_bf16(Af1, Bf, acc[1], 0, 0, 0);
  }
  int dd = d0 + c*16 + li;
  float* Fp = Fpart + ((size_t)(ks*2 + b)) * 65536;
  for (int i = 0; i < 2; i++){
    int dor = do0 + r*32 + i*16 + lgp*4;
    float* p = Fp + (size_t)dor*256 + dd;
    p[0]   = acc[i][0];
    p[256] = acc[i][1];
    p[512] = acc[i][2];
    p[768] = acc[i][3];
  }
}

// =============== reduce Fpart over ks -> Fb (bf16 [b][do][d]) ===============
__global__ __launch_bounds__(256) void k_fred(const float* __restrict__ Fpart,
                                              unsigned short* __restrict__ Fb){
  int idx = blockIdx.x * 256 + threadIdx.x;    // 32768 threads x 4 elems
  int b = idx >> 14; int e4 = (idx & 16383) * 4;
  f32x4 s = (f32x4){0,0,0,0};
  for (int ks = 0; ks < 8; ks++){
    f32x4 v = *(const f32x4*)(Fpart + ((size_t)(ks*2 + b)) * 65536 + e4);
    s[0] += v[0]; s[1] += v[1]; s[2] += v[2]; s[3] += v[3];
  }
  *(unsigned long long*)(Fb + (size_t)b*65536 + e4) = pk4(s[0], s[1], s[2], s[3]);
}

// =============== out[tok][do] = x @ F(bf16) + c0 (f32 direct) ===============
__global__ __launch_bounds__(512) void k_final2(const unsigned short* __restrict__ Fb,
                                                const unsigned short* __restrict__ xb,
                                                const float* __restrict__ c0acc,
                                                float* __restrict__ out){
  int bid = blockIdx.x;                        // 64 = b(2) * tc(32), 64 tokens each
  int tc = bid & 31, b = bid >> 5;
  int t = threadIdx.x, lane = t & 63, w = t >> 6;
  int li = lane & 15, lgp = lane >> 4;
  int r = w >> 1, c = w & 1;                   // r: do 4x64, c: tok 2x32
  int tok0 = b * 2048 + tc * 64;
  f32x4 acc[4][2];
  for (int i = 0; i < 4; i++) for (int j = 0; j < 2; j++) acc[i][j] = (f32x4){0,0,0,0};
  for (int kk = 0; kk < 8; kk++){
    bf16x8 Bf[2];
    for (int j = 0; j < 2; j++)
      Bf[j] = *(const bf16x8*)(xb + (size_t)(tok0 + c*32 + j*16 + li)*256 + kk*32 + lgp*8);
    for (int i = 0; i < 4; i++){
      bf16x8 af = *(const bf16x8*)(Fb + (size_t)b*65536 + (size_t)(r*64 + i*16 + li)*256 + kk*32 + lgp*8);
      for (int j = 0; j < 2; j++)
        acc[i][j] = __builtin_amdgcn_mfma_f32_16x16x32_bf16(af, Bf[j], acc[i][j], 0, 0, 0);
    }
  }
  // C row=do, col=tok: direct f32x4 stores (sector-complete per wave)
  for (int i = 0; i < 4; i++){
    int dol = r*64 + i*16 + lgp*4;
    f32x4 c4 = *(const f32x4*)(c0acc + (size_t)b*256 + dol);
    for (int j = 0; j < 2; j++){
      int tokl = c*32 + j*16 + li;
      f32x4 v = acc[i][j];
      v[0] += c4[0]; v[1] += c4[1]; v[2] += c4[2]; v[3] += c4[3];
      *(f32x4*)(out + (size_t)(tok0 + tokl)*256 + dol) = v;
    }
  }
}

extern "C" void kernel_launch(void* const* d_in, const int* in_sizes, int n_in,
                              void* d_out, int out_size, void* d_ws, size_t ws_size,
                              hipStream_t stream) {
  const float* x     = (const float*)d_in[0];
  const float* Wq    = (const float*)d_in[1];
  const float* bq    = (const float*)d_in[2];
  const float* Wr    = (const float*)d_in[3];
  const float* br    = (const float*)d_in[4];
  const float* Wk    = (const float*)d_in[5];
  const float* bk    = (const float*)d_in[6];
  const float* Wv    = (const float*)d_in[7];
  const float* bv    = (const float*)d_in[8];
  const float* Wo    = (const float*)d_in[9];
  const float* bo    = (const float*)d_in[10];
  const float* bias0 = (const float*)d_in[11];
  float* out = (float*)d_out;

  char* ws = (char*)d_ws;
  size_t off = 0;
  auto alloc = [&](size_t bytes) -> char* {
    char* p = ws + off;
    off = (off + bytes + 255) & ~(size_t)255;
    return p;
  };
  unsigned short* xb   = (unsigned short*)alloc((size_t)4096 * 256 * 2);      // 2 MB
  unsigned short* xT   = (unsigned short*)alloc((size_t)2 * 256 * 2048 * 2);  // 2 MB
  unsigned short* Wqb  = (unsigned short*)alloc((size_t)256 * 2048 * 2);      // 1 MB
  unsigned short* WkT  = (unsigned short*)alloc((size_t)8 * 2048 * 256 * 2);  // 8 MB
  unsigned short* WvT  = (unsigned short*)alloc((size_t)8 * 2048 * 256 * 2);  // 8 MB
  unsigned short* WoT  = (unsigned short*)alloc((size_t)256 * 2048 * 2);      // 1 MB
  float*          routT= (float*)alloc((size_t)16 * 2048 * 4);                // 128 KB
  float*          upart= (float*)alloc((size_t)256 * 256 * 4);                // 256 KB
  float*          rhop = (float*)alloc((size_t)256 * 4);
  float*          rho  = (float*)alloc((size_t)16 * 4);
  float*          ku_g = (float*)alloc((size_t)16 * 2048 * 4);
  float*          vu_g = (float*)alloc((size_t)16 * 2048 * 4);
  unsigned short* Gp   = (unsigned short*)alloc((size_t)16 * 8 * 65536 * 2);  // 16 MB
  unsigned short* G    = (unsigned short*)alloc((size_t)16 * 65536 * 2);      // 2 MB
  unsigned short* memT = (unsigned short*)alloc((size_t)16 * 65536 * 2);      // 2 MB
  unsigned short* Eb   = (unsigned short*)alloc((size_t)2 * 256 * 2048 * 2);  // 2 MB
  float*          qbAll= (float*)alloc((size_t)2 * 2048 * 4);
  float*          Fpart= (float*)alloc((size_t)16 * 65536 * 4);               // 4 MB
  unsigned short* Fb   = (unsigned short*)alloc((size_t)2 * 65536 * 2);       // 256 KB
  float*          c0acc= (float*)alloc((size_t)2 * 256 * 4);
  (void)ws_size; (void)in_sizes; (void)n_in; (void)out_size;

  k_prep<<<10112, 256, 0, stream>>>(x, Wq, Wr, br, Wk, Wv, Wo, bias0,
                                    WkT, WvT, WoT, Wqb, xb, xT, routT);
  k_usum<<<256, 256, 0, stream>>>(xb, routT, upart, rhop);
  k_bias<<<128, 256, 0, stream>>>(WkT, WvT, upart, rhop, ku_g, vu_g, rho);
  k_gpart<<<128, 512, 0, stream>>>(xT, routT, Gp);
  k_gred<<<512, 256, 0, stream>>>(Gp, G);
  k_mem2<<<128, 512, 0, stream>>>(G, WkT, WvT, bk, bv, ku_g, vu_g, rho, memT);
  k_emat<<<64, 512, 0, stream>>>(memT, Wqb, bq, Eb, qbAll);
  k_fmat<<<258, 512, 0, stream>>>(Eb, WoT, qbAll, bo, Fpart, c0acc);
  k_fred<<<128, 256, 0, stream>>>(Fpart, Fb);
  k_final2<<<64, 512, 0, stream>>>(Fb, xb, c0acc, out);
}

// Round 12
// 208.155 us; speedup vs baseline: 1.1828x; 1.1828x over previous
//
#include <hip/hip_runtime.h>

typedef __attribute__((ext_vector_type(8))) short bf16x8;
typedef __attribute__((ext_vector_type(4))) float f32x4;

#define DEV static __device__ __forceinline__

DEV unsigned short f2bf(float f){
  union { float f; unsigned u; } v; v.f = f;
  unsigned r = v.u + 0x7fffu + ((v.u >> 16) & 1u);
  return (unsigned short)(r >> 16);
}
DEV float bf2f(unsigned short u){
  union { unsigned u; float f; } v; v.u = ((unsigned)u) << 16;
  return v.f;
}
DEV unsigned long long pk4(float a, float b, float c, float d){
  unsigned lo = (unsigned)f2bf(a) | ((unsigned)f2bf(b) << 16);
  unsigned hi = (unsigned)f2bf(c) | ((unsigned)f2bf(d) << 16);
  return ((unsigned long long)hi << 32) | lo;
}

// =============== fused prep: weight transposes/converts + x prep + router ===============
__global__ __launch_bounds__(256) void k_prep(const float* __restrict__ x,
                                              const float* __restrict__ Wq,
                                              const float* __restrict__ Wr,
                                              const float* __restrict__ br,
                                              const float* __restrict__ Wk,
                                              const float* __restrict__ Wv,
                                              const float* __restrict__ Wo,
                                              const float* __restrict__ bias0,
                                              unsigned short* __restrict__ WkT,
                                              unsigned short* __restrict__ WvT,
                                              unsigned short* __restrict__ WoT,
                                              unsigned short* __restrict__ Wqb,
                                              unsigned short* __restrict__ xb,
                                              unsigned short* __restrict__ xT,
                                              float* __restrict__ routT){
  __shared__ float tile[32*33];
  __shared__ float lg[32][8];
  __shared__ float rt2[32][8];
  int bid = blockIdx.x;
  int t = threadIdx.x;
  int tx = t & 31, ty = t >> 5;

  if (bid < 8192){                      // Wk (0..4095) / Wv (4096..8191): [8][256][2048] -> [8][2048][256]
    const float* src = (bid < 4096) ? Wk : Wv;
    unsigned short* dst = (bid < 4096) ? WkT : WvT;
    int q = bid & 4095;
    int bat = q >> 9, rem = q & 511;
    int c0 = (rem >> 3) * 32, r0 = (rem & 7) * 32;
    size_t boff = (size_t)bat * 256 * 2048;
    for (int i = 0; i < 4; i++)
      tile[(ty + i*8)*33 + tx] = src[boff + (size_t)(r0 + ty + i*8) * 2048 + c0 + tx];
    __syncthreads();
    for (int i = 0; i < 4; i++)
      dst[boff + (size_t)(c0 + ty + i*8) * 256 + r0 + tx] = f2bf(tile[tx*33 + ty + i*8]);
  } else if (bid < 8704){               // Wo: [2048][256] -> [256][2048]
    int q = bid - 8192;
    int c0 = (q >> 6) * 32, r0 = (q & 63) * 32;
    for (int i = 0; i < 4; i++)
      tile[(ty + i*8)*33 + tx] = Wo[(size_t)(r0 + ty + i*8) * 256 + c0 + tx];
    __syncthreads();
    for (int i = 0; i < 4; i++)
      WoT[(size_t)(c0 + ty + i*8) * 2048 + r0 + tx] = f2bf(tile[tx*33 + ty + i*8]);
  } else if (bid < 8960){               // Wq plain convert [256][2048]
    int q = bid - 8704;
    size_t idx = (size_t)q * 2048 + t * 8;
    f32x4 a = *(const f32x4*)(Wq + idx);
    f32x4 b = *(const f32x4*)(Wq + idx + 4);
    *(unsigned long long*)(Wqb + idx)     = pk4(a[0], a[1], a[2], a[3]);
    *(unsigned long long*)(Wqb + idx + 4) = pk4(b[0], b[1], b[2], b[3]);
  } else if (bid < 9984){               // x: [2][2048][256] -> xb [4096][256] + xT [2][256][2048]
    int q = bid - 8960;
    int bat = q >> 9, rem = q & 511;
    int c0 = (rem >> 6) * 32, r0 = (rem & 63) * 32;
    size_t boff = (size_t)bat * 2048 * 256;
    for (int i = 0; i < 4; i++){
      float v = x[boff + (size_t)(r0 + ty + i*8) * 256 + c0 + tx];
      tile[(ty + i*8)*33 + tx] = v;
      xb[boff + (size_t)(r0 + ty + i*8) * 256 + c0 + tx] = f2bf(v);
    }
    __syncthreads();
    for (int i = 0; i < 4; i++)
      xT[(size_t)(bat*256 + c0 + ty + i*8) * 2048 + r0 + tx] = f2bf(tile[tx*33 + ty + i*8]);
  } else {                              // router: 128 blocks, 32 tokens each
    int row = t >> 3, mm = t & 7;
    int n = (bid - 9984) * 32 + row;
    const float* xr = x + (size_t)n * 256;
    float acc = 0.f;
    for (int d = 0; d < 256; d++) acc += xr[d] * Wr[d * 8 + mm];
    acc += br[mm];
    lg[row][mm] = acc;
    __syncthreads();
    if (t < 32){
      int r = t; int n2 = (bid - 9984) * 32 + r; int b = n2 >> 11;
      float mx = -1e30f;
      for (int i = 0; i < 8; i++) mx = fmaxf(mx, lg[r][i]);
      float s[8]; float sum = 0.f;
      for (int i = 0; i < 8; i++){ s[i] = __expf(lg[r][i] - mx); sum += s[i]; }
      for (int i = 0; i < 8; i++) s[i] /= sum;
      float bb[8];
      for (int i = 0; i < 8; i++) bb[i] = s[i] + bias0[b * 8 + i];
      int i1 = 0;
      for (int i = 1; i < 8; i++) if (bb[i] > bb[i1]) i1 = i;
      int i2 = -1;
      for (int i = 0; i < 8; i++){ if (i == i1) continue; if (i2 < 0 || bb[i] > bb[i2]) i2 = i; }
      float wsum = s[i1] + s[i2];
      for (int i = 0; i < 8; i++)
        rt2[r][i] = (i == i1) ? s[i1] / wsum : ((i == i2) ? s[i2] / wsum : 0.f);
    }
    __syncthreads();
    int n3 = (bid - 9984) * 32 + row;
    int b = n3 >> 11, sl = n3 & 2047;
    routT[((size_t)b * 8 + mm) * 2048 + sl] = rt2[row][mm];
  }
}

// =============== upart[bm*16+sc][d] = sum_{s in chunk} r*x ; rhop[bm*16+sc] (no atomics) ===============
__global__ __launch_bounds__(256) void k_usum(const unsigned short* __restrict__ xb,
                                              const float* __restrict__ routT,
                                              float* __restrict__ upart, float* __restrict__ rhop){
  __shared__ float rl[128];
  int bid = blockIdx.x;                 // 256 = bm(16) * sc(16)
  int sc = bid & 15, bm = bid >> 4, b = bm >> 3;
  int t = threadIdx.x;
  int s0 = sc * 128;
  if (t < 128) rl[t] = routT[(size_t)bm * 2048 + s0 + t];
  __syncthreads();
  float acc = 0.f;
  const unsigned short* xrow = xb + ((size_t)(b * 2048 + s0)) * 256 + t;
  for (int s = 0; s < 128; s++){
    float rv = rl[s];
    if (rv != 0.f)
      acc += rv * bf2f(xrow[(size_t)s * 256]);
  }
  upart[(size_t)bid * 256 + t] = acc;
  if (t == 0){
    float rs = 0.f;
    for (int s = 0; s < 128; s++) rs += rl[s];
    rhop[bid] = rs;
  }
}

// =============== ku/vu = WkT/WvT . u (u summed from partials in-block); rho emitted ===============
__global__ __launch_bounds__(256) void k_bias(const unsigned short* __restrict__ WkT,
                                              const unsigned short* __restrict__ WvT,
                                              const float* __restrict__ upart,
                                              const float* __restrict__ rhop,
                                              float* __restrict__ ku_g, float* __restrict__ vu_g,
                                              float* __restrict__ rho){
  __shared__ float uL[256];
  int bid = blockIdx.x, t = threadIdx.x;
  int bm = bid >> 3, hseg = bid & 7, m = bm & 7;
  {
    float s = 0.f;
    for (int scn = 0; scn < 16; scn++)
      s += upart[(size_t)(bm*16 + scn) * 256 + t];
    uL[t] = s;
  }
  if (hseg == 0 && t == 0){
    float rs = 0.f;
    for (int scn = 0; scn < 16; scn++) rs += rhop[bm*16 + scn];
    rho[bm] = rs;
  }
  __syncthreads();
  int hd = hseg * 256 + t;
  const unsigned short* wk = WkT + ((size_t)m*2048 + hd) * 256;
  const unsigned short* wv = WvT + ((size_t)m*2048 + hd) * 256;
  float sk = 0.f, sv = 0.f;
  for (int d8 = 0; d8 < 256; d8 += 8){
    bf16x8 a = *(const bf16x8*)(wk + d8);
    bf16x8 c = *(const bf16x8*)(wv + d8);
    for (int j = 0; j < 8; j++){
      sk += bf2f((unsigned short)a[j]) * uL[d8+j];
      sv += bf2f((unsigned short)c[j]) * uL[d8+j];
    }
  }
  ku_g[(size_t)bm*2048 + hd] = sk;
  vu_g[(size_t)bm*2048 + hd] = sv;
}

// =============== Gp[bm][kc] = X_chunk^T diag(r) X_chunk (256x256, K=256 tokens) ===============
__global__ __launch_bounds__(512) void k_gpart(const unsigned short* __restrict__ xT,
                                               const float* __restrict__ routT,
                                               unsigned short* __restrict__ Gp){
  __shared__ unsigned short As[256*72];     // scaled, 36 KB
  __shared__ unsigned short Bs[256*72];     // unscaled, 36 KB
  __shared__ float rl[64];
  int bid = blockIdx.x;                      // 128 = b(2) m(8) kc(8)
  int kc = bid & 7, m = (bid >> 3) & 7, b = bid >> 6;
  int bm = b * 8 + m;
  int t = threadIdx.x, lane = t & 63, w = t >> 6;
  int li = lane & 15, lgp = lane >> 4;
  int p = w >> 2, q = w & 3;
  f32x4 acc[8][4];
  for (int i = 0; i < 8; i++) for (int j = 0; j < 4; j++) acc[i][j] = (f32x4){0,0,0,0};
  for (int c4 = 0; c4 < 4; c4++){
    int s0 = kc * 256 + c4 * 64;
    if (t < 64) rl[t] = routT[(size_t)bm*2048 + s0 + t];
    __syncthreads();
    for (int qq = 0; qq < 4; qq++){
      int idx = t + qq*512;
      int row = idx >> 3, sc = (idx & 7) * 8;
      bf16x8 xv = *(const bf16x8*)(xT + ((size_t)(b*256 + row))*2048 + s0 + sc);
      *(bf16x8*)(&Bs[row*72 + sc]) = xv;
      f32x4 r0 = *(const f32x4*)(rl + sc);
      f32x4 r1 = *(const f32x4*)(rl + sc + 4);
      bf16x8 sv;
      sv[0]=(short)f2bf(bf2f((unsigned short)xv[0])*r0[0]);
      sv[1]=(short)f2bf(bf2f((unsigned short)xv[1])*r0[1]);
      sv[2]=(short)f2bf(bf2f((unsigned short)xv[2])*r0[2]);
      sv[3]=(short)f2bf(bf2f((unsigned short)xv[3])*r0[3]);
      sv[4]=(short)f2bf(bf2f((unsigned short)xv[4])*r1[0]);
      sv[5]=(short)f2bf(bf2f((unsigned short)xv[5])*r1[1]);
      sv[6]=(short)f2bf(bf2f((unsigned short)xv[6])*r1[2]);
      sv[7]=(short)f2bf(bf2f((unsigned short)xv[7])*r1[3]);
      *(bf16x8*)(&As[row*72 + sc]) = sv;
    }
    __syncthreads();
    for (int kk = 0; kk < 2; kk++){
      bf16x8 Bf[4];
      for (int j = 0; j < 4; j++)
        Bf[j] = *(const bf16x8*)(&Bs[(q*64 + j*16 + li)*72 + kk*32 + lgp*8]);
      for (int i = 0; i < 8; i++){
        bf16x8 Af = *(const bf16x8*)(&As[(p*128 + i*16 + li)*72 + kk*32 + lgp*8]);
        for (int j = 0; j < 4; j++)
          acc[i][j] = __builtin_amdgcn_mfma_f32_16x16x32_bf16(Af, Bf[j], acc[i][j], 0, 0, 0);
      }
    }
    __syncthreads();
  }
  // bounce C (col=d1 from A-pack, row=d2 from B-li) -> Gp[bm][kc][d2][d1]
  unsigned short* Cs = As;                   // 64 x 264 overlay
  for (int ph = 0; ph < 4; ph++){
    if (q == ph){
      for (int i = 0; i < 8; i++)
        for (int j = 0; j < 4; j++){
          int rr = j*16 + li, cc = p*128 + i*16 + lgp*4;
          *(unsigned long long*)(&Cs[rr*264 + cc]) =
            pk4(acc[i][j][0], acc[i][j][1], acc[i][j][2], acc[i][j][3]);
        }
    }
    __syncthreads();
    for (int qq = 0; qq < 4; qq++){
      int idx = t + qq*512;
      int row = idx >> 5, cc = (idx & 31) * 8;
      *(bf16x8*)(Gp + (((size_t)bm*8 + kc) << 16) + (size_t)(ph*64 + row)*256 + cc) =
        *(const bf16x8*)(&Cs[row*264 + cc]);
    }
    __syncthreads();
  }
}

// =============== reduce Gp over kc -> G[bm][256][256] ===============
__global__ __launch_bounds__(256) void k_gred(const unsigned short* __restrict__ Gp,
                                              unsigned short* __restrict__ G){
  int idx = blockIdx.x * 256 + threadIdx.x;
  int bm = idx >> 13; size_t e8 = (size_t)(idx & 8191) * 8;
  float s[8] = {0,0,0,0,0,0,0,0};
  for (int kc = 0; kc < 8; kc++){
    bf16x8 v = *(const bf16x8*)(Gp + (((size_t)bm*8 + kc) << 16) + e8);
    for (int j = 0; j < 8; j++) s[j] += bf2f((unsigned short)v[j]);
  }
  *(unsigned long long*)(G + ((size_t)bm << 16) + e8)     = pk4(s[0], s[1], s[2], s[3]);
  *(unsigned long long*)(G + ((size_t)bm << 16) + e8 + 4) = pk4(s[4], s[5], s[6], s[7]);
}

// =============== Tt[bm][vd(hd) 2048][d1 256] = (G[bm] @ Wv_m)^T  (register GEMM) ===============
__global__ __launch_bounds__(512) void k_tmat(const unsigned short* __restrict__ G,
                                              const unsigned short* __restrict__ WvT,
                                              unsigned short* __restrict__ Tt){
  __shared__ unsigned short Cs[64*264];        // 34 KB bounce
  int bid = blockIdx.x;                         // 256 = bm(16) * hseg(16)
  int hseg = bid & 15, bm = bid >> 4, m = bm & 7;
  int t = threadIdx.x, lane = t & 63, w = t >> 6;
  int li = lane & 15, lgp = lane >> 4;
  int r = w >> 1, c = w & 1;                    // r: d1 quarter(64), c: vd half(64)
  f32x4 acc[4][4];
  for (int i = 0; i < 4; i++) for (int j = 0; j < 4; j++) acc[i][j] = (f32x4){0,0,0,0};
  const unsigned short* gp = G + ((size_t)bm << 16) + (size_t)(r*64 + li)*256 + lgp*8;
  const unsigned short* wp = WvT + ((size_t)m*2048 + hseg*128 + c*64 + li)*256 + lgp*8;
  #pragma unroll
  for (int kk = 0; kk < 8; kk++){
    bf16x8 Bf[4];
    for (int j = 0; j < 4; j++)
      Bf[j] = *(const bf16x8*)(wp + (size_t)(j*16)*256 + kk*32);
    for (int i = 0; i < 4; i++){
      bf16x8 Af = *(const bf16x8*)(gp + (size_t)(i*16)*256 + kk*32);
      for (int j = 0; j < 4; j++)
        acc[i][j] = __builtin_amdgcn_mfma_f32_16x16x32_bf16(Af, Bf[j], acc[i][j], 0, 0, 0);
    }
  }
  // bounce: C[vd = c*64+j*16+li][d1 = r*64+i*16+lgp*4] -> Tt rows, 2 phases
  for (int ph = 0; ph < 2; ph++){
    if (c == ph){
      for (int i = 0; i < 4; i++)
        for (int j = 0; j < 4; j++)
          *(unsigned long long*)(&Cs[(j*16 + li)*264 + r*64 + i*16 + lgp*4]) =
            pk4(acc[i][j][0], acc[i][j][1], acc[i][j][2], acc[i][j][3]);
    }
    __syncthreads();
    for (int q = 0; q < 4; q++){
      int idx = t + q*512;
      int row = idx >> 5, cc = (idx & 31) * 8;
      *(bf16x8*)(Tt + ((size_t)bm*2048 + hseg*128 + ph*64 + row)*256 + cc) =
        *(const bf16x8*)(&Cs[row*264 + cc]);
    }
    __syncthreads();
  }
}

// =============== mempartF[m][bh][vq][kq] (128x128 f32) = Tt_m x WkT_m (barrier-free, per-m blocks) ===============
__global__ __launch_bounds__(512) void k_kmat3(const unsigned short* __restrict__ Tt,
                                               const unsigned short* __restrict__ WkT,
                                               float* __restrict__ mempartF){
  int bid = blockIdx.x;                         // 512 = bh(16) x vq(2) x kq(2) x m(8)
  int m = bid & 7, kq = (bid >> 3) & 1, vq = (bid >> 4) & 1, bh = bid >> 5;
  int b = bh >> 3, h = bh & 7;
  int hd0 = h * 256;
  int t = threadIdx.x, lane = t & 63, w = t >> 6;
  int li = lane & 15, lgp = lane >> 4;
  int wr = w >> 2, wc = w & 3;                  // wave grid: vd 2x64, kd 4x32
  f32x4 acc[2][4];                              // [i: kd 16-blk][j: vd 16-blk]
  for (int i = 0; i < 2; i++) for (int j = 0; j < 4; j++) acc[i][j] = (f32x4){0,0,0,0};
  const unsigned short* ap = WkT + ((size_t)m*2048 + hd0 + kq*128 + wc*32 + li)*256 + lgp*8;
  const unsigned short* bp = Tt + ((size_t)(b*8 + m)*2048 + hd0 + vq*128 + wr*64 + li)*256 + lgp*8;
  #pragma unroll
  for (int kk = 0; kk < 8; kk++){
    bf16x8 Af[2], Bf[4];
    Af[0] = *(const bf16x8*)(ap + kk*32);
    Af[1] = *(const bf16x8*)(ap + 16*256 + kk*32);
    for (int j = 0; j < 4; j++)
      Bf[j] = *(const bf16x8*)(bp + (size_t)(j*16)*256 + kk*32);
    for (int i = 0; i < 2; i++)
      for (int j = 0; j < 4; j++)
        acc[i][j] = __builtin_amdgcn_mfma_f32_16x16x32_bf16(Af[i], Bf[j], acc[i][j], 0, 0, 0);
  }
  // store f32 partial tile [vdt 128][kdt 128]
  float* Fp = mempartF + ((((size_t)(m*16 + bh))*2 + vq)*2 + kq) * 16384;
  for (int j = 0; j < 4; j++){
    int vdt = wr*64 + j*16 + li;
    for (int i = 0; i < 2; i++){
      int kdt = wc*32 + i*16 + lgp*4;
      *(f32x4*)(Fp + (size_t)vdt*128 + kdt) = acc[i][j];
    }
  }
}

// =============== k_kred: memT[bh][vd][kd] = Sum_m mempartF + rank-1 epilogue ===============
__global__ __launch_bounds__(256) void k_kred(const float* __restrict__ mempartF,
                                              const float* __restrict__ bk,
                                              const float* __restrict__ bv,
                                              const float* __restrict__ ku_g,
                                              const float* __restrict__ vu_g,
                                              const float* __restrict__ rho,
                                              unsigned short* __restrict__ memT){
  int idx = blockIdx.x * 256 + threadIdx.x;     // 262144 = 16bh x 256vd x 64(kd/4)
  int bh = idx >> 14;
  int rem = idx & 16383;
  int vd = rem >> 6, kd = (rem & 63) * 4;
  int b = bh >> 3, h = bh & 7;
  int vdg = h*256 + vd, kdg = h*256 + kd;
  int vq = vd >> 7, kq = kd >> 7;
  size_t src = ((((size_t)bh)*2 + vq)*2 + kq) * 16384 + (size_t)(vd & 127)*128 + (kd & 127);
  f32x4 s = (f32x4){0,0,0,0};
  #pragma unroll
  for (int m = 0; m < 8; m++){
    f32x4 v = *(const f32x4*)(mempartF + (size_t)m*16*65536 + src);
    s[0] += v[0]; s[1] += v[1]; s[2] += v[2]; s[3] += v[3];
  }
  #pragma unroll
  for (int m = 0; m < 8; m++){
    float bvv = bv[(size_t)m*2048 + vdg];
    float bb  = vu_g[(size_t)(b*8+m)*2048 + vdg] + rho[b*8+m]*bvv;
    f32x4 ku4 = *(const f32x4*)(ku_g + (size_t)(b*8+m)*2048 + kdg);
    f32x4 bk4 = *(const f32x4*)(bk + (size_t)m*2048 + kdg);
    s[0] += ku4[0]*bvv + bk4[0]*bb;
    s[1] += ku4[1]*bvv + bk4[1]*bb;
    s[2] += ku4[2]*bvv + bk4[2]*bb;
    s[3] += ku4[3]*bvv + bk4[3]*bb;
  }
  *(unsigned long long*)(memT + (size_t)bh*65536 + (size_t)vd*256 + kd) =
    pk4(s[0], s[1], s[2], s[3]);
}

// =============== E_h = Wq_h @ mem_h  -> Eb[b][d][h*256+vd]; qbAll = bq_h . mem_h ===============
__global__ __launch_bounds__(512) void k_emat(const unsigned short* __restrict__ memT,
                                              const unsigned short* __restrict__ Wqb,
                                              const float* __restrict__ bq,
                                              unsigned short* __restrict__ Eb,
                                              float* __restrict__ qbAll){
  __shared__ unsigned short Cs[16*264];
  int bid = blockIdx.x;                        // 64 = bh(16) * dseg(4)
  int dseg = bid & 3, bh = bid >> 2;
  int b = bh >> 3, h = bh & 7;
  int hd0 = h * 256, d0 = dseg * 64;
  int t = threadIdx.x, lane = t & 63, w = t >> 6;
  int li = lane & 15, lgp = lane >> 4;
  int r = w >> 2, c = w & 3;                   // r: vd half(128), c: d quarter(16)
  f32x4 acc[8];
  for (int i = 0; i < 8; i++) acc[i] = (f32x4){0,0,0,0};
  for (int kk = 0; kk < 8; kk++){
    bf16x8 Bf = *(const bf16x8*)(Wqb + (size_t)(d0 + c*16 + li)*2048 + hd0 + kk*32 + lgp*8);
    for (int i = 0; i < 8; i++){
      bf16x8 Af = *(const bf16x8*)(memT + (size_t)bh*65536 + (size_t)(r*128 + i*16 + li)*256 + kk*32 + lgp*8);
      acc[i] = __builtin_amdgcn_mfma_f32_16x16x32_bf16(Af, Bf, acc[i], 0, 0, 0);
    }
  }
  if (dseg == 0 && t < 256){
    const unsigned short* mrow = memT + (size_t)bh*65536 + (size_t)t*256;
    float s = 0.f;
    for (int k8 = 0; k8 < 256; k8 += 8){
      bf16x8 v = *(const bf16x8*)(mrow + k8);
      for (int e = 0; e < 8; e++) s += bf2f((unsigned short)v[e]) * bq[hd0 + k8 + e];
    }
    qbAll[(size_t)b*2048 + hd0 + t] = s;
  }
  for (int ph = 0; ph < 4; ph++){
    if (c == ph){
      for (int i = 0; i < 8; i++)
        *(unsigned long long*)(&Cs[li*264 + r*128 + i*16 + lgp*4]) =
          pk4(acc[i][0], acc[i][1], acc[i][2], acc[i][3]);
    }
    __syncthreads();
    {
      int row = t >> 5, cc = (t & 31) * 8;     // 16 rows x 256 cols
      *(bf16x8*)(Eb + (size_t)b*524288 + (size_t)(d0 + ph*16 + row)*2048 + hd0 + cc) =
        *(const bf16x8*)(&Cs[row*264 + cc]);
    }
    __syncthreads();
  }
}

// =============== Fpart[ks][b][do][d] = Eb x Wo slice-K (split-K 8); tail: c0 wave-parallel ===============
__global__ __launch_bounds__(512) void k_fmat(const unsigned short* __restrict__ Eb,
                                              const unsigned short* __restrict__ WoT,
                                              const float* __restrict__ qbAll,
                                              const float* __restrict__ bo,
                                              float* __restrict__ Fpart,
                                              float* __restrict__ c0acc){
  __shared__ float qL[2048];
  int bid = blockIdx.x;
  int t = threadIdx.x;
  if (bid >= 256){                             // c0 blocks: bid 256,257 -> b (wave-parallel matvec)
    int b = bid - 256;
    for (int i = t; i < 2048; i += 512) qL[i] = qbAll[(size_t)b * 2048 + i];
    __syncthreads();
    int w = t >> 6, lane = t & 63;
    for (int dd = w; dd < 256; dd += 8){
      const unsigned short* wrow = WoT + (size_t)dd * 2048 + lane * 8;
      const float* qp = qL + lane * 8;
      float s = 0.f;
      for (int pass = 0; pass < 4; pass++){
        bf16x8 v = *(const bf16x8*)(wrow + pass * 512);
        const float* q = qp + pass * 512;
        for (int e = 0; e < 8; e++) s += bf2f((unsigned short)v[e]) * q[e];
      }
      for (int off = 32; off; off >>= 1) s += __shfl_down(s, off);
      if (lane == 0) c0acc[(size_t)b * 256 + dd] = s + bo[dd];
    }
    return;
  }
  // F blocks: 256 = b(2) x doseg(4) x dseg(4) x ks(8); 64x64 tile, K = 256
  int ks = bid & 7, dseg = (bid >> 3) & 3, doseg = (bid >> 5) & 3, b = bid >> 7;
  int do0 = doseg * 64, d0 = dseg * 64, k0 = ks * 256;
  int lane = t & 63, w = t >> 6;
  int li = lane & 15, lgp = lane >> 4;
  int r = w >> 2, c = w & 3;                   // r: do 2x32, c: d 4x16
  f32x4 acc[2];
  acc[0] = (f32x4){0,0,0,0}; acc[1] = (f32x4){0,0,0,0};
  const unsigned short* bp = Eb + (size_t)b*524288 + (size_t)(d0 + c*16 + li)*2048 + k0 + lgp*8;
  const unsigned short* ap = WoT + (size_t)(do0 + r*32 + li)*2048 + k0 + lgp*8;
  #pragma unroll
  for (int kk = 0; kk < 8; kk++){
    bf16x8 Bf = *(const bf16x8*)(bp + kk*32);
    bf16x8 Af0 = *(const bf16x8*)(ap + kk*32);
    bf16x8 Af1 = *(const bf16x8*)(ap + kk*32 + 16*2048);
    acc[0] = __builtin_amdgcn_mfma_f32_16x16x32_bf16(Af0, Bf, acc[0], 0, 0, 0);
    acc[1] = __builtin_amdgcn_mfma_f32_16x16x32_bf16(Af1, Bf, acc[1], 0, 0, 0);
  }
  int dd = d0 + c*16 + li;
  float* Fp = Fpart + ((size_t)(ks*2 + b)) * 65536;
  for (int i = 0; i < 2; i++){
    int dor = do0 + r*32 + i*16 + lgp*4;
    float* p = Fp + (size_t)dor*256 + dd;
    p[0]   = acc[i][0];
    p[256] = acc[i][1];
    p[512] = acc[i][2];
    p[768] = acc[i][3];
  }
}

// =============== reduce Fpart over ks -> Fb (bf16 [b][do][d]) ===============
__global__ __launch_bounds__(256) void k_fred(const float* __restrict__ Fpart,
                                              unsigned short* __restrict__ Fb){
  int idx = blockIdx.x * 256 + threadIdx.x;    // 32768 threads x 4 elems
  int b = idx >> 14; int e4 = (idx & 16383) * 4;
  f32x4 s = (f32x4){0,0,0,0};
  for (int ks = 0; ks < 8; ks++){
    f32x4 v = *(const f32x4*)(Fpart + ((size_t)(ks*2 + b)) * 65536 + e4);
    s[0] += v[0]; s[1] += v[1]; s[2] += v[2]; s[3] += v[3];
  }
  *(unsigned long long*)(Fb + (size_t)b*65536 + e4) = pk4(s[0], s[1], s[2], s[3]);
}

// =============== out[tok][do] = x @ F(bf16) + c0 (f32 direct) ===============
__global__ __launch_bounds__(512) void k_final2(const unsigned short* __restrict__ Fb,
                                                const unsigned short* __restrict__ xb,
                                                const float* __restrict__ c0acc,
                                                float* __restrict__ out){
  int bid = blockIdx.x;                        // 64 = b(2) * tc(32), 64 tokens each
  int tc = bid & 31, b = bid >> 5;
  int t = threadIdx.x, lane = t & 63, w = t >> 6;
  int li = lane & 15, lgp = lane >> 4;
  int r = w >> 1, c = w & 1;                   // r: do 4x64, c: tok 2x32
  int tok0 = b * 2048 + tc * 64;
  f32x4 acc[4][2];
  for (int i = 0; i < 4; i++) for (int j = 0; j < 2; j++) acc[i][j] = (f32x4){0,0,0,0};
  for (int kk = 0; kk < 8; kk++){
    bf16x8 Bf[2];
    for (int j = 0; j < 2; j++)
      Bf[j] = *(const bf16x8*)(xb + (size_t)(tok0 + c*32 + j*16 + li)*256 + kk*32 + lgp*8);
    for (int i = 0; i < 4; i++){
      bf16x8 af = *(const bf16x8*)(Fb + (size_t)b*65536 + (size_t)(r*64 + i*16 + li)*256 + kk*32 + lgp*8);
      for (int j = 0; j < 2; j++)
        acc[i][j] = __builtin_amdgcn_mfma_f32_16x16x32_bf16(af, Bf[j], acc[i][j], 0, 0, 0);
    }
  }
  for (int i = 0; i < 4; i++){
    int dol = r*64 + i*16 + lgp*4;
    f32x4 c4 = *(const f32x4*)(c0acc + (size_t)b*256 + dol);
    for (int j = 0; j < 2; j++){
      int tokl = c*32 + j*16 + li;
      f32x4 v = acc[i][j];
      v[0] += c4[0]; v[1] += c4[1]; v[2] += c4[2]; v[3] += c4[3];
      *(f32x4*)(out + (size_t)(tok0 + tokl)*256 + dol) = v;
    }
  }
}

extern "C" void kernel_launch(void* const* d_in, const int* in_sizes, int n_in,
                              void* d_out, int out_size, void* d_ws, size_t ws_size,
                              hipStream_t stream) {
  const float* x     = (const float*)d_in[0];
  const float* Wq    = (const float*)d_in[1];
  const float* bq    = (const float*)d_in[2];
  const float* Wr    = (const float*)d_in[3];
  const float* br    = (const float*)d_in[4];
  const float* Wk    = (const float*)d_in[5];
  const float* bk    = (const float*)d_in[6];
  const float* Wv    = (const float*)d_in[7];
  const float* bv    = (const float*)d_in[8];
  const float* Wo    = (const float*)d_in[9];
  const float* bo    = (const float*)d_in[10];
  const float* bias0 = (const float*)d_in[11];
  float* out = (float*)d_out;

  char* ws = (char*)d_ws;
  size_t off = 0;
  auto alloc = [&](size_t bytes) -> char* {
    char* p = ws + off;
    off = (off + bytes + 255) & ~(size_t)255;
    return p;
  };
  unsigned short* xb   = (unsigned short*)alloc((size_t)4096 * 256 * 2);      // 2 MB
  unsigned short* xT   = (unsigned short*)alloc((size_t)2 * 256 * 2048 * 2);  // 2 MB
  unsigned short* Wqb  = (unsigned short*)alloc((size_t)256 * 2048 * 2);      // 1 MB
  unsigned short* WkT  = (unsigned short*)alloc((size_t)8 * 2048 * 256 * 2);  // 8 MB
  unsigned short* WvT  = (unsigned short*)alloc((size_t)8 * 2048 * 256 * 2);  // 8 MB
  unsigned short* WoT  = (unsigned short*)alloc((size_t)256 * 2048 * 2);      // 1 MB
  float*          routT= (float*)alloc((size_t)16 * 2048 * 4);                // 128 KB
  float*          upart= (float*)alloc((size_t)256 * 256 * 4);                // 256 KB
  float*          rhop = (float*)alloc((size_t)256 * 4);
  float*          rho  = (float*)alloc((size_t)16 * 4);
  float*          ku_g = (float*)alloc((size_t)16 * 2048 * 4);
  float*          vu_g = (float*)alloc((size_t)16 * 2048 * 4);
  unsigned short* Gp   = (unsigned short*)alloc((size_t)16 * 8 * 65536 * 2);  // 16 MB
  unsigned short* G    = (unsigned short*)alloc((size_t)16 * 65536 * 2);      // 2 MB
  unsigned short* memT = (unsigned short*)alloc((size_t)16 * 65536 * 2);      // 2 MB
  unsigned short* Eb   = (unsigned short*)alloc((size_t)2 * 256 * 2048 * 2);  // 2 MB
  float*          qbAll= (float*)alloc((size_t)2 * 2048 * 4);
  float*          Fpart= (float*)alloc((size_t)16 * 65536 * 4);               // 4 MB
  unsigned short* Fb   = (unsigned short*)alloc((size_t)2 * 65536 * 2);       // 256 KB
  float*          c0acc= (float*)alloc((size_t)2 * 256 * 4);
  float*          mempartF = (float*)alloc((size_t)8 * 16 * 65536 * 4);       // 32 MB
  unsigned short* Tt   = Gp;      // alias: Gp dead after k_gred; Tt = 16x2048x256 bf16 = 16 MB
  (void)ws_size; (void)in_sizes; (void)n_in; (void)out_size;

  k_prep<<<10112, 256, 0, stream>>>(x, Wq, Wr, br, Wk, Wv, Wo, bias0,
                                    WkT, WvT, WoT, Wqb, xb, xT, routT);
  k_usum<<<256, 256, 0, stream>>>(xb, routT, upart, rhop);
  k_bias<<<128, 256, 0, stream>>>(WkT, WvT, upart, rhop, ku_g, vu_g, rho);
  k_gpart<<<128, 512, 0, stream>>>(xT, routT, Gp);
  k_gred<<<512, 256, 0, stream>>>(Gp, G);
  k_tmat<<<256, 512, 0, stream>>>(G, WvT, Tt);
  k_kmat3<<<512, 512, 0, stream>>>(Tt, WkT, mempartF);
  k_kred<<<1024, 256, 0, stream>>>(mempartF, bk, bv, ku_g, vu_g, rho, memT);
  k_emat<<<64, 512, 0, stream>>>(memT, Wqb, bq, Eb, qbAll);
  k_fmat<<<258, 512, 0, stream>>>(Eb, WoT, qbAll, bo, Fpart, c0acc);
  k_fred<<<128, 256, 0, stream>>>(Fpart, Fb);
  k_final2<<<64, 512, 0, stream>>>(Fb, xb, c0acc, out);
}

// Round 14
// 194.471 us; speedup vs baseline: 1.2660x; 1.0704x over previous
//
#include <hip/hip_runtime.h>

typedef __attribute__((ext_vector_type(8))) short bf16x8;
typedef __attribute__((ext_vector_type(4))) float f32x4;

#define DEV static __device__ __forceinline__

DEV unsigned short f2bf(float f){
  union { float f; unsigned u; } v; v.f = f;
  unsigned r = v.u + 0x7fffu + ((v.u >> 16) & 1u);
  return (unsigned short)(r >> 16);
}
DEV float bf2f(unsigned short u){
  union { unsigned u; float f; } v; v.u = ((unsigned)u) << 16;
  return v.f;
}
DEV unsigned long long pk4(float a, float b, float c, float d){
  unsigned lo = (unsigned)f2bf(a) | ((unsigned)f2bf(b) << 16);
  unsigned hi = (unsigned)f2bf(c) | ((unsigned)f2bf(d) << 16);
  return ((unsigned long long)hi << 32) | lo;
}

// =============== fused prep (64x64 tiles, full-line writes) ===============
__global__ __launch_bounds__(256) void k_prep(const float* __restrict__ x,
                                              const float* __restrict__ Wq,
                                              const float* __restrict__ Wr,
                                              const float* __restrict__ br,
                                              const float* __restrict__ Wk,
                                              const float* __restrict__ Wv,
                                              const float* __restrict__ Wo,
                                              const float* __restrict__ bias0,
                                              unsigned short* __restrict__ WkT,
                                              unsigned short* __restrict__ WvT,
                                              unsigned short* __restrict__ WoT,
                                              unsigned short* __restrict__ Wqb,
                                              unsigned short* __restrict__ xb,
                                              unsigned short* __restrict__ xT,
                                              float* __restrict__ routT){
  __shared__ float tile[64*65];          // 16.6 KB
  __shared__ float lg[32][8];
  __shared__ float rt2[32][8];
  int bid = blockIdx.x;
  int t = threadIdx.x;
  int tx = t & 63, ty = t >> 6;          // 64 x 4

  if (bid < 2048){                       // Wk (0..1023) / Wv (1024..2047): [8][256][2048] -> [8][2048][256]
    const float* src = (bid < 1024) ? Wk : Wv;
    unsigned short* dst = (bid < 1024) ? WkT : WvT;
    int q = bid & 1023;
    int bat = q >> 7, rem = q & 127;
    int c0 = (rem >> 2) * 64, r0 = (rem & 3) * 64;     // c0: hd(2048), r0: d(256)
    size_t boff = (size_t)bat * 256 * 2048;
    for (int i = 0; i < 16; i++)
      tile[(ty + i*4)*65 + tx] = src[boff + (size_t)(r0 + ty + i*4) * 2048 + c0 + tx];
    __syncthreads();
    for (int i = 0; i < 16; i++)
      dst[boff + (size_t)(c0 + ty + i*4) * 256 + r0 + tx] = f2bf(tile[tx*65 + ty + i*4]);
  } else if (bid < 2176){                // Wo: [2048][256] -> [256][2048]
    int q = bid - 2048;
    int r0 = (q >> 2) * 64, c0 = (q & 3) * 64;         // r0: 2048-dim, c0: 256-dim
    for (int i = 0; i < 16; i++)
      tile[(ty + i*4)*65 + tx] = Wo[(size_t)(r0 + ty + i*4) * 256 + c0 + tx];
    __syncthreads();
    for (int i = 0; i < 16; i++)
      WoT[(size_t)(c0 + ty + i*4) * 2048 + r0 + tx] = f2bf(tile[tx*65 + ty + i*4]);
  } else if (bid < 2432){                // Wq plain convert [256][2048]
    int q = bid - 2176;
    size_t idx = (size_t)q * 2048 + t * 8;
    f32x4 a = *(const f32x4*)(Wq + idx);
    f32x4 b = *(const f32x4*)(Wq + idx + 4);
    *(unsigned long long*)(Wqb + idx)     = pk4(a[0], a[1], a[2], a[3]);
    *(unsigned long long*)(Wqb + idx + 4) = pk4(b[0], b[1], b[2], b[3]);
  } else if (bid < 2688){                // x: [2][2048][256] -> xb + xT
    int q = bid - 2432;
    int bat = q >> 7, rem = q & 127;
    int r0 = (rem >> 2) * 64, c0 = (rem & 3) * 64;     // r0: s(2048), c0: d(256)
    size_t boff = (size_t)bat * 2048 * 256;
    for (int i = 0; i < 16; i++){
      float v = x[boff + (size_t)(r0 + ty + i*4) * 256 + c0 + tx];
      tile[(ty + i*4)*65 + tx] = v;
      xb[boff + (size_t)(r0 + ty + i*4) * 256 + c0 + tx] = f2bf(v);
    }
    __syncthreads();
    for (int i = 0; i < 16; i++)
      xT[(size_t)(bat*256 + c0 + ty + i*4) * 2048 + r0 + tx] = f2bf(tile[tx*65 + ty + i*4]);
  } else {                               // router: 128 blocks, 32 tokens each
    int row = t >> 3, mm = t & 7;
    int n = (bid - 2688) * 32 + row;
    const float* xr = x + (size_t)n * 256;
    float acc = 0.f;
    for (int d = 0; d < 256; d++) acc += xr[d] * Wr[d * 8 + mm];
    acc += br[mm];
    lg[row][mm] = acc;
    __syncthreads();
    if (t < 32){
      int r = t; int n2 = (bid - 2688) * 32 + r; int b = n2 >> 11;
      float mx = -1e30f;
      for (int i = 0; i < 8; i++) mx = fmaxf(mx, lg[r][i]);
      float s[8]; float sum = 0.f;
      for (int i = 0; i < 8; i++){ s[i] = __expf(lg[r][i] - mx); sum += s[i]; }
      for (int i = 0; i < 8; i++) s[i] /= sum;
      float bb[8];
      for (int i = 0; i < 8; i++) bb[i] = s[i] + bias0[b * 8 + i];
      int i1 = 0;
      for (int i = 1; i < 8; i++) if (bb[i] > bb[i1]) i1 = i;
      int i2 = -1;
      for (int i = 0; i < 8; i++){ if (i == i1) continue; if (i2 < 0 || bb[i] > bb[i2]) i2 = i; }
      float wsum = s[i1] + s[i2];
      for (int i = 0; i < 8; i++)
        rt2[r][i] = (i == i1) ? s[i1] / wsum : ((i == i2) ? s[i2] / wsum : 0.f);
    }
    __syncthreads();
    int n3 = (bid - 2688) * 32 + row;
    int b = n3 >> 11, sl = n3 & 2047;
    routT[((size_t)b * 8 + mm) * 2048 + sl] = rt2[row][mm];
  }
}

// =============== upart[bm*16+sc][d] = sum_{s in chunk} r*x ; rhop (no atomics) ===============
__global__ __launch_bounds__(256) void k_usum(const unsigned short* __restrict__ xb,
                                              const float* __restrict__ routT,
                                              float* __restrict__ upart, float* __restrict__ rhop){
  __shared__ float rl[128];
  int bid = blockIdx.x;                 // 256 = bm(16) * sc(16)
  int sc = bid & 15, bm = bid >> 4, b = bm >> 3;
  int t = threadIdx.x;
  int s0 = sc * 128;
  if (t < 128) rl[t] = routT[(size_t)bm * 2048 + s0 + t];
  __syncthreads();
  float acc = 0.f;
  const unsigned short* xrow = xb + ((size_t)(b * 2048 + s0)) * 256 + t;
  for (int s = 0; s < 128; s++){
    float rv = rl[s];
    if (rv != 0.f)
      acc += rv * bf2f(xrow[(size_t)s * 256]);
  }
  upart[(size_t)bid * 256 + t] = acc;
  if (t == 0){
    float rs = 0.f;
    for (int s = 0; s < 128; s++) rs += rl[s];
    rhop[bid] = rs;
  }
}

// =============== ku/vu = WkT/WvT . u ; rho emitted ===============
__global__ __launch_bounds__(256) void k_bias(const unsigned short* __restrict__ WkT,
                                              const unsigned short* __restrict__ WvT,
                                              const float* __restrict__ upart,
                                              const float* __restrict__ rhop,
                                              float* __restrict__ ku_g, float* __restrict__ vu_g,
                                              float* __restrict__ rho){
  __shared__ float uL[256];
  int bid = blockIdx.x, t = threadIdx.x;
  int bm = bid >> 3, hseg = bid & 7, m = bm & 7;
  {
    float s = 0.f;
    for (int scn = 0; scn < 16; scn++)
      s += upart[(size_t)(bm*16 + scn) * 256 + t];
    uL[t] = s;
  }
  if (hseg == 0 && t == 0){
    float rs = 0.f;
    for (int scn = 0; scn < 16; scn++) rs += rhop[bm*16 + scn];
    rho[bm] = rs;
  }
  __syncthreads();
  int hd = hseg * 256 + t;
  const unsigned short* wk = WkT + ((size_t)m*2048 + hd) * 256;
  const unsigned short* wv = WvT + ((size_t)m*2048 + hd) * 256;
  float sk = 0.f, sv = 0.f;
  for (int d8 = 0; d8 < 256; d8 += 8){
    bf16x8 a = *(const bf16x8*)(wk + d8);
    bf16x8 c = *(const bf16x8*)(wv + d8);
    for (int j = 0; j < 8; j++){
      sk += bf2f((unsigned short)a[j]) * uL[d8+j];
      sv += bf2f((unsigned short)c[j]) * uL[d8+j];
    }
  }
  ku_g[(size_t)bm*2048 + hd] = sk;
  vu_g[(size_t)bm*2048 + hd] = sv;
}

// =============== Gp[bm][kc] = X_chunk^T diag(r) X_chunk ===============
__global__ __launch_bounds__(512) void k_gpart(const unsigned short* __restrict__ xT,
                                               const float* __restrict__ routT,
                                               unsigned short* __restrict__ Gp){
  __shared__ unsigned short As[256*72];
  __shared__ unsigned short Bs[256*72];
  __shared__ float rl[64];
  int bid = blockIdx.x;                      // 128 = b(2) m(8) kc(8)
  int kc = bid & 7, m = (bid >> 3) & 7, b = bid >> 6;
  int bm = b * 8 + m;
  int t = threadIdx.x, lane = t & 63, w = t >> 6;
  int li = lane & 15, lgp = lane >> 4;
  int p = w >> 2, q = w & 3;
  f32x4 acc[8][4];
  for (int i = 0; i < 8; i++) for (int j = 0; j < 4; j++) acc[i][j] = (f32x4){0,0,0,0};
  for (int c4 = 0; c4 < 4; c4++){
    int s0 = kc * 256 + c4 * 64;
    if (t < 64) rl[t] = routT[(size_t)bm*2048 + s0 + t];
    __syncthreads();
    for (int qq = 0; qq < 4; qq++){
      int idx = t + qq*512;
      int row = idx >> 3, sc = (idx & 7) * 8;
      bf16x8 xv = *(const bf16x8*)(xT + ((size_t)(b*256 + row))*2048 + s0 + sc);
      *(bf16x8*)(&Bs[row*72 + sc]) = xv;
      f32x4 r0 = *(const f32x4*)(rl + sc);
      f32x4 r1 = *(const f32x4*)(rl + sc + 4);
      bf16x8 sv;
      sv[0]=(short)f2bf(bf2f((unsigned short)xv[0])*r0[0]);
      sv[1]=(short)f2bf(bf2f((unsigned short)xv[1])*r0[1]);
      sv[2]=(short)f2bf(bf2f((unsigned short)xv[2])*r0[2]);
      sv[3]=(short)f2bf(bf2f((unsigned short)xv[3])*r0[3]);
      sv[4]=(short)f2bf(bf2f((unsigned short)xv[4])*r1[0]);
      sv[5]=(short)f2bf(bf2f((unsigned short)xv[5])*r1[1]);
      sv[6]=(short)f2bf(bf2f((unsigned short)xv[6])*r1[2]);
      sv[7]=(short)f2bf(bf2f((unsigned short)xv[7])*r1[3]);
      *(bf16x8*)(&As[row*72 + sc]) = sv;
    }
    __syncthreads();
    for (int kk = 0; kk < 2; kk++){
      bf16x8 Bf[4];
      for (int j = 0; j < 4; j++)
        Bf[j] = *(const bf16x8*)(&Bs[(q*64 + j*16 + li)*72 + kk*32 + lgp*8]);
      for (int i = 0; i < 8; i++){
        bf16x8 Af = *(const bf16x8*)(&As[(p*128 + i*16 + li)*72 + kk*32 + lgp*8]);
        for (int j = 0; j < 4; j++)
          acc[i][j] = __builtin_amdgcn_mfma_f32_16x16x32_bf16(Af, Bf[j], acc[i][j], 0, 0, 0);
      }
    }
    __syncthreads();
  }
  unsigned short* Cs = As;                   // 64 x 264 overlay
  for (int ph = 0; ph < 4; ph++){
    if (q == ph){
      for (int i = 0; i < 8; i++)
        for (int j = 0; j < 4; j++){
          int rr = j*16 + li, cc = p*128 + i*16 + lgp*4;
          *(unsigned long long*)(&Cs[rr*264 + cc]) =
            pk4(acc[i][j][0], acc[i][j][1], acc[i][j][2], acc[i][j][3]);
        }
    }
    __syncthreads();
    for (int qq = 0; qq < 4; qq++){
      int idx = t + qq*512;
      int row = idx >> 5, cc = (idx & 31) * 8;
      *(bf16x8*)(Gp + (((size_t)bm*8 + kc) << 16) + (size_t)(ph*64 + row)*256 + cc) =
        *(const bf16x8*)(&Cs[row*264 + cc]);
    }
    __syncthreads();
  }
}

// =============== reduce Gp over kc -> G ===============
__global__ __launch_bounds__(256) void k_gred(const unsigned short* __restrict__ Gp,
                                              unsigned short* __restrict__ G){
  int idx = blockIdx.x * 256 + threadIdx.x;
  int bm = idx >> 13; size_t e8 = (size_t)(idx & 8191) * 8;
  float s[8] = {0,0,0,0,0,0,0,0};
  for (int kc = 0; kc < 8; kc++){
    bf16x8 v = *(const bf16x8*)(Gp + (((size_t)bm*8 + kc) << 16) + e8);
    for (int j = 0; j < 8; j++) s[j] += bf2f((unsigned short)v[j]);
  }
  *(unsigned long long*)(G + ((size_t)bm << 16) + e8)     = pk4(s[0], s[1], s[2], s[3]);
  *(unsigned long long*)(G + ((size_t)bm << 16) + e8 + 4) = pk4(s[4], s[5], s[6], s[7]);
}

// =============== Tt[bm][vd(hd) 2048][d1 256] = (G[bm] @ Wv_m)^T ===============
__global__ __launch_bounds__(512) void k_tmat(const unsigned short* __restrict__ G,
                                              const unsigned short* __restrict__ WvT,
                                              unsigned short* __restrict__ Tt){
  __shared__ unsigned short Cs[64*264];
  int bid = blockIdx.x;                         // 256 = bm(16) * hseg(16)
  int hseg = bid & 15, bm = bid >> 4, m = bm & 7;
  int t = threadIdx.x, lane = t & 63, w = t >> 6;
  int li = lane & 15, lgp = lane >> 4;
  int r = w >> 1, c = w & 1;
  f32x4 acc[4][4];
  for (int i = 0; i < 4; i++) for (int j = 0; j < 4; j++) acc[i][j] = (f32x4){0,0,0,0};
  const unsigned short* gp = G + ((size_t)bm << 16) + (size_t)(r*64 + li)*256 + lgp*8;
  const unsigned short* wp = WvT + ((size_t)m*2048 + hseg*128 + c*64 + li)*256 + lgp*8;
  #pragma unroll
  for (int kk = 0; kk < 8; kk++){
    bf16x8 Bf[4];
    for (int j = 0; j < 4; j++)
      Bf[j] = *(const bf16x8*)(wp + (size_t)(j*16)*256 + kk*32);
    for (int i = 0; i < 4; i++){
      bf16x8 Af = *(const bf16x8*)(gp + (size_t)(i*16)*256 + kk*32);
      for (int j = 0; j < 4; j++)
        acc[i][j] = __builtin_amdgcn_mfma_f32_16x16x32_bf16(Af, Bf[j], acc[i][j], 0, 0, 0);
    }
  }
  for (int ph = 0; ph < 2; ph++){
    if (c == ph){
      for (int i = 0; i < 4; i++)
        for (int j = 0; j < 4; j++)
          *(unsigned long long*)(&Cs[(j*16 + li)*264 + r*64 + i*16 + lgp*4]) =
            pk4(acc[i][j][0], acc[i][j][1], acc[i][j][2], acc[i][j][3]);
    }
    __syncthreads();
    for (int q = 0; q < 4; q++){
      int idx = t + q*512;
      int row = idx >> 5, cc = (idx & 31) * 8;
      *(bf16x8*)(Tt + ((size_t)bm*2048 + hseg*128 + ph*64 + row)*256 + cc) =
        *(const bf16x8*)(&Cs[row*264 + cc]);
    }
    __syncthreads();
  }
}

// =============== mempartB[m][h][vq][kq][b] (128x128 bf16) = Tt_m x WkT_m (both b per block) ===============
__global__ __launch_bounds__(512) void k_kmat3(const unsigned short* __restrict__ Tt,
                                               const unsigned short* __restrict__ WkT,
                                               unsigned short* __restrict__ mempartB){
  int bid = blockIdx.x;                         // 256 = h(8) vq(2) kq(2) m(8)
  int m = bid & 7, kq = (bid >> 3) & 1, vq = (bid >> 4) & 1, h = bid >> 5;
  int hd0 = h * 256;
  int t = threadIdx.x, lane = t & 63, w = t >> 6;
  int li = lane & 15, lgp = lane >> 4;
  int wr = w >> 2, wc = w & 3;                  // vd 2x64-blk, kd 4x32-blk
  f32x4 acc[2][2][4];                           // [b][i: kd16][j: vd16]
  for (int b = 0; b < 2; b++)
    for (int i = 0; i < 2; i++)
      for (int j = 0; j < 4; j++) acc[b][i][j] = (f32x4){0,0,0,0};
  const unsigned short* ap  = WkT + ((size_t)m*2048 + hd0 + kq*128 + wc*32 + li)*256 + lgp*8;
  const unsigned short* bp0 = Tt + ((size_t)(m)*2048 + hd0 + vq*128 + wr*64 + li)*256 + lgp*8;
  const unsigned short* bp1 = Tt + ((size_t)(8 + m)*2048 + hd0 + vq*128 + wr*64 + li)*256 + lgp*8;
  #pragma unroll
  for (int kk = 0; kk < 8; kk++){
    bf16x8 Af[2], B0[4], B1[4];
    Af[0] = *(const bf16x8*)(ap + kk*32);
    Af[1] = *(const bf16x8*)(ap + 16*256 + kk*32);
    for (int j = 0; j < 4; j++){
      B0[j] = *(const bf16x8*)(bp0 + (size_t)(j*16)*256 + kk*32);
      B1[j] = *(const bf16x8*)(bp1 + (size_t)(j*16)*256 + kk*32);
    }
    for (int i = 0; i < 2; i++)
      for (int j = 0; j < 4; j++){
        acc[0][i][j] = __builtin_amdgcn_mfma_f32_16x16x32_bf16(Af[i], B0[j], acc[0][i][j], 0, 0, 0);
        acc[1][i][j] = __builtin_amdgcn_mfma_f32_16x16x32_bf16(Af[i], B1[j], acc[1][i][j], 0, 0, 0);
      }
  }
  // store bf16 partial tiles [vdt 128][kdt 128]
  for (int b = 0; b < 2; b++){
    unsigned short* Fp = mempartB + ((((((size_t)m*8 + h)*2 + vq)*2 + kq)*2 + b)) * 16384;
    for (int j = 0; j < 4; j++){
      int vdt = wr*64 + j*16 + li;
      for (int i = 0; i < 2; i++){
        int kdt = wc*32 + i*16 + lgp*4;
        *(unsigned long long*)(Fp + (size_t)vdt*128 + kdt) =
          pk4(acc[b][i][j][0], acc[b][i][j][1], acc[b][i][j][2], acc[b][i][j][3]);
      }
    }
  }
}

// =============== k_kred: memT[bh][vd][kd] = Sum_m mempartB + rank-1 epilogue ===============
__global__ __launch_bounds__(256) void k_kred(const unsigned short* __restrict__ mempartB,
                                              const float* __restrict__ bk,
                                              const float* __restrict__ bv,
                                              const float* __restrict__ ku_g,
                                              const float* __restrict__ vu_g,
                                              const float* __restrict__ rho,
                                              unsigned short* __restrict__ memT){
  int idx = blockIdx.x * 256 + threadIdx.x;     // 262144 = 16bh x 256vd x 64(kd/4)
  int bh = idx >> 14;
  int rem = idx & 16383;
  int vd = rem >> 6, kd = (rem & 63) * 4;
  int b = bh >> 3, h = bh & 7;
  int vdg = h*256 + vd, kdg = h*256 + kd;
  int vq = vd >> 7, kq = kd >> 7;
  size_t src = ((((size_t)h*2 + vq)*2 + kq)*2 + b) * 16384 + (size_t)(vd & 127)*128 + (kd & 127);
  f32x4 s = (f32x4){0,0,0,0};
  #pragma unroll
  for (int m = 0; m < 8; m++){
    // per-m extent = 8h * 2vq * 2kq * 2b * 16384 = 1048576 elements
    unsigned long long v = *(const unsigned long long*)(mempartB + (size_t)m*1048576 + src);
    s[0] += bf2f((unsigned short)v);
    s[1] += bf2f((unsigned short)(v >> 16));
    s[2] += bf2f((unsigned short)(v >> 32));
    s[3] += bf2f((unsigned short)(v >> 48));
  }
  #pragma unroll
  for (int m = 0; m < 8; m++){
    float bvv = bv[(size_t)m*2048 + vdg];
    float bb  = vu_g[(size_t)(b*8+m)*2048 + vdg] + rho[b*8+m]*bvv;
    f32x4 ku4 = *(const f32x4*)(ku_g + (size_t)(b*8+m)*2048 + kdg);
    f32x4 bk4 = *(const f32x4*)(bk + (size_t)m*2048 + kdg);
    s[0] += ku4[0]*bvv + bk4[0]*bb;
    s[1] += ku4[1]*bvv + bk4[1]*bb;
    s[2] += ku4[2]*bvv + bk4[2]*bb;
    s[3] += ku4[3]*bvv + bk4[3]*bb;
  }
  *(unsigned long long*)(memT + (size_t)bh*65536 + (size_t)vd*256 + kd) =
    pk4(s[0], s[1], s[2], s[3]);
}

// =============== E_h = Wq_h @ mem_h -> Eb; qbAll = bq_h . mem_h ===============
__global__ __launch_bounds__(512) void k_emat(const unsigned short* __restrict__ memT,
                                              const unsigned short* __restrict__ Wqb,
                                              const float* __restrict__ bq,
                                              unsigned short* __restrict__ Eb,
                                              float* __restrict__ qbAll){
  __shared__ unsigned short Cs[16*264];
  int bid = blockIdx.x;                        // 64 = bh(16) * dseg(4)
  int dseg = bid & 3, bh = bid >> 2;
  int b = bh >> 3, h = bh & 7;
  int hd0 = h * 256, d0 = dseg * 64;
  int t = threadIdx.x, lane = t & 63, w = t >> 6;
  int li = lane & 15, lgp = lane >> 4;
  int r = w >> 2, c = w & 3;
  f32x4 acc[8];
  for (int i = 0; i < 8; i++) acc[i] = (f32x4){0,0,0,0};
  for (int kk = 0; kk < 8; kk++){
    bf16x8 Bf = *(const bf16x8*)(Wqb + (size_t)(d0 + c*16 + li)*2048 + hd0 + kk*32 + lgp*8);
    for (int i = 0; i < 8; i++){
      bf16x8 Af = *(const bf16x8*)(memT + (size_t)bh*65536 + (size_t)(r*128 + i*16 + li)*256 + kk*32 + lgp*8);
      acc[i] = __builtin_amdgcn_mfma_f32_16x16x32_bf16(Af, Bf, acc[i], 0, 0, 0);
    }
  }
  if (dseg == 0 && t < 256){
    const unsigned short* mrow = memT + (size_t)bh*65536 + (size_t)t*256;
    float s = 0.f;
    for (int k8 = 0; k8 < 256; k8 += 8){
      bf16x8 v = *(const bf16x8*)(mrow + k8);
      for (int e = 0; e < 8; e++) s += bf2f((unsigned short)v[e]) * bq[hd0 + k8 + e];
    }
    qbAll[(size_t)b*2048 + hd0 + t] = s;
  }
  for (int ph = 0; ph < 4; ph++){
    if (c == ph){
      for (int i = 0; i < 8; i++)
        *(unsigned long long*)(&Cs[li*264 + r*128 + i*16 + lgp*4]) =
          pk4(acc[i][0], acc[i][1], acc[i][2], acc[i][3]);
    }
    __syncthreads();
    {
      int row = t >> 5, cc = (t & 31) * 8;
      *(bf16x8*)(Eb + (size_t)b*524288 + (size_t)(d0 + ph*16 + row)*2048 + hd0 + cc) =
        *(const bf16x8*)(&Cs[row*264 + cc]);
    }
    __syncthreads();
  }
}

// =============== Fpart = Eb x Wo slice-K (split-K 8); tail: c0 ===============
__global__ __launch_bounds__(512) void k_fmat(const unsigned short* __restrict__ Eb,
                                              const unsigned short* __restrict__ WoT,
                                              const float* __restrict__ qbAll,
                                              const float* __restrict__ bo,
                                              float* __restrict__ Fpart,
                                              float* __restrict__ c0acc){
  __shared__ float qL[2048];
  int bid = blockIdx.x;
  int t = threadIdx.x;
  if (bid >= 256){
    int b = bid - 256;
    for (int i = t; i < 2048; i += 512) qL[i] = qbAll[(size_t)b * 2048 + i];
    __syncthreads();
    int w = t >> 6, lane = t & 63;
    for (int dd = w; dd < 256; dd += 8){
      const unsigned short* wrow = WoT + (size_t)dd * 2048 + lane * 8;
      const float* qp = qL + lane * 8;
      float s = 0.f;
      for (int pass = 0; pass < 4; pass++){
        bf16x8 v = *(const bf16x8*)(wrow + pass * 512);
        const float* q = qp + pass * 512;
        for (int e = 0; e < 8; e++) s += bf2f((unsigned short)v[e]) * q[e];
      }
      for (int off = 32; off; off >>= 1) s += __shfl_down(s, off);
      if (lane == 0) c0acc[(size_t)b * 256 + dd] = s + bo[dd];
    }
    return;
  }
  int ks = bid & 7, dseg = (bid >> 3) & 3, doseg = (bid >> 5) & 3, b = bid >> 7;
  int do0 = doseg * 64, d0 = dseg * 64, k0 = ks * 256;
  int lane = t & 63, w = t >> 6;
  int li = lane & 15, lgp = lane >> 4;
  int r = w >> 2, c = w & 3;
  f32x4 acc[2];
  acc[0] = (f32x4){0,0,0,0}; acc[1] = (f32x4){0,0,0,0};
  const unsigned short* bp = Eb + (size_t)b*524288 + (size_t)(d0 + c*16 + li)*2048 + k0 + lgp*8;
  const unsigned short* ap = WoT + (size_t)(do0 + r*32 + li)*2048 + k0 + lgp*8;
  #pragma unroll
  for (int kk = 0; kk < 8; kk++){
    bf16x8 Bf = *(const bf16x8*)(bp + kk*32);
    bf16x8 Af0 = *(const bf16x8*)(ap + kk*32);
    bf16x8 Af1 = *(const bf16x8*)(ap + kk*32 + 16*2048);
    acc[0] = __builtin_amdgcn_mfma_f32_16x16x32_bf16(Af0, Bf, acc[0], 0, 0, 0);
    acc[1] = __builtin_amdgcn_mfma_f32_16x16x32_bf16(Af1, Bf, acc[1], 0, 0, 0);
  }
  int dd = d0 + c*16 + li;
  float* Fp = Fpart + ((size_t)(ks*2 + b)) * 65536;
  for (int i = 0; i < 2; i++){
    int dor = do0 + r*32 + i*16 + lgp*4;
    float* p = Fp + (size_t)dor*256 + dd;
    p[0]   = acc[i][0];
    p[256] = acc[i][1];
    p[512] = acc[i][2];
    p[768] = acc[i][3];
  }
}

// =============== reduce Fpart over ks -> Fb ===============
__global__ __launch_bounds__(256) void k_fred(const float* __restrict__ Fpart,
                                              unsigned short* __restrict__ Fb){
  int idx = blockIdx.x * 256 + threadIdx.x;
  int b = idx >> 14; int e4 = (idx & 16383) * 4;
  f32x4 s = (f32x4){0,0,0,0};
  for (int ks = 0; ks < 8; ks++){
    f32x4 v = *(const f32x4*)(Fpart + ((size_t)(ks*2 + b)) * 65536 + e4);
    s[0] += v[0]; s[1] += v[1]; s[2] += v[2]; s[3] += v[3];
  }
  *(unsigned long long*)(Fb + (size_t)b*65536 + e4) = pk4(s[0], s[1], s[2], s[3]);
}

// =============== out[tok][do] = x @ F(bf16) + c0 ===============
__global__ __launch_bounds__(512) void k_final2(const unsigned short* __restrict__ Fb,
                                                const unsigned short* __restrict__ xb,
                                                const float* __restrict__ c0acc,
                                                float* __restrict__ out){
  int bid = blockIdx.x;                        // 64 = b(2) * tc(32)
  int tc = bid & 31, b = bid >> 5;
  int t = threadIdx.x, lane = t & 63, w = t >> 6;
  int li = lane & 15, lgp = lane >> 4;
  int r = w >> 1, c = w & 1;
  int tok0 = b * 2048 + tc * 64;
  f32x4 acc[4][2];
  for (int i = 0; i < 4; i++) for (int j = 0; j < 2; j++) acc[i][j] = (f32x4){0,0,0,0};
  for (int kk = 0; kk < 8; kk++){
    bf16x8 Bf[2];
    for (int j = 0; j < 2; j++)
      Bf[j] = *(const bf16x8*)(xb + (size_t)(tok0 + c*32 + j*16 + li)*256 + kk*32 + lgp*8);
    for (int i = 0; i < 4; i++){
      bf16x8 af = *(const bf16x8*)(Fb + (size_t)b*65536 + (size_t)(r*64 + i*16 + li)*256 + kk*32 + lgp*8);
      for (int j = 0; j < 2; j++)
        acc[i][j] = __builtin_amdgcn_mfma_f32_16x16x32_bf16(af, Bf[j], acc[i][j], 0, 0, 0);
    }
  }
  for (int i = 0; i < 4; i++){
    int dol = r*64 + i*16 + lgp*4;
    f32x4 c4 = *(const f32x4*)(c0acc + (size_t)b*256 + dol);
    for (int j = 0; j < 2; j++){
      int tokl = c*32 + j*16 + li;
      f32x4 v = acc[i][j];
      v[0] += c4[0]; v[1] += c4[1]; v[2] += c4[2]; v[3] += c4[3];
      *(f32x4*)(out + (size_t)(tok0 + tokl)*256 + dol) = v;
    }
  }
}

extern "C" void kernel_launch(void* const* d_in, const int* in_sizes, int n_in,
                              void* d_out, int out_size, void* d_ws, size_t ws_size,
                              hipStream_t stream) {
  const float* x     = (const float*)d_in[0];
  const float* Wq    = (const float*)d_in[1];
  const float* bq    = (const float*)d_in[2];
  const float* Wr    = (const float*)d_in[3];
  const float* br    = (const float*)d_in[4];
  const float* Wk    = (const float*)d_in[5];
  const float* bk    = (const float*)d_in[6];
  const float* Wv    = (const float*)d_in[7];
  const float* bv    = (const float*)d_in[8];
  const float* Wo    = (const float*)d_in[9];
  const float* bo    = (const float*)d_in[10];
  const float* bias0 = (const float*)d_in[11];
  float* out = (float*)d_out;

  char* ws = (char*)d_ws;
  size_t off = 0;
  auto alloc = [&](size_t bytes) -> char* {
    char* p = ws + off;
    off = (off + bytes + 255) & ~(size_t)255;
    return p;
  };
  unsigned short* xb   = (unsigned short*)alloc((size_t)4096 * 256 * 2);      // 2 MB
  unsigned short* xT   = (unsigned short*)alloc((size_t)2 * 256 * 2048 * 2);  // 2 MB
  unsigned short* Wqb  = (unsigned short*)alloc((size_t)256 * 2048 * 2);      // 1 MB
  unsigned short* WkT  = (unsigned short*)alloc((size_t)8 * 2048 * 256 * 2);  // 8 MB
  unsigned short* WvT  = (unsigned short*)alloc((size_t)8 * 2048 * 256 * 2);  // 8 MB
  unsigned short* WoT  = (unsigned short*)alloc((size_t)256 * 2048 * 2);      // 1 MB
  float*          routT= (float*)alloc((size_t)16 * 2048 * 4);                // 128 KB
  float*          upart= (float*)alloc((size_t)256 * 256 * 4);                // 256 KB
  float*          rhop = (float*)alloc((size_t)256 * 4);
  float*          rho  = (float*)alloc((size_t)16 * 4);
  float*          ku_g = (float*)alloc((size_t)16 * 2048 * 4);
  float*          vu_g = (float*)alloc((size_t)16 * 2048 * 4);
  unsigned short* Gp   = (unsigned short*)alloc((size_t)16 * 8 * 65536 * 2);  // 16 MB
  unsigned short* G    = (unsigned short*)alloc((size_t)16 * 65536 * 2);      // 2 MB
  unsigned short* memT = (unsigned short*)alloc((size_t)16 * 65536 * 2);      // 2 MB
  unsigned short* Eb   = (unsigned short*)alloc((size_t)2 * 256 * 2048 * 2);  // 2 MB
  float*          qbAll= (float*)alloc((size_t)2 * 2048 * 4);
  float*          Fpart= (float*)alloc((size_t)16 * 65536 * 4);               // 4 MB
  unsigned short* Fb   = (unsigned short*)alloc((size_t)2 * 65536 * 2);       // 256 KB
  float*          c0acc= (float*)alloc((size_t)2 * 256 * 4);
  unsigned short* mempartB = (unsigned short*)alloc((size_t)8 * 1048576 * 2); // 16 MB
  unsigned short* Tt   = Gp;      // alias: Gp dead after k_gred
  (void)ws_size; (void)in_sizes; (void)n_in; (void)out_size;

  k_prep<<<2816, 256, 0, stream>>>(x, Wq, Wr, br, Wk, Wv, Wo, bias0,
                                   WkT, WvT, WoT, Wqb, xb, xT, routT);
  k_usum<<<256, 256, 0, stream>>>(xb, routT, upart, rhop);
  k_bias<<<128, 256, 0, stream>>>(WkT, WvT, upart, rhop, ku_g, vu_g, rho);
  k_gpart<<<128, 512, 0, stream>>>(xT, routT, Gp);
  k_gred<<<512, 256, 0, stream>>>(Gp, G);
  k_tmat<<<256, 512, 0, stream>>>(G, WvT, Tt);
  k_kmat3<<<256, 512, 0, stream>>>(Tt, WkT, mempartB);
  k_kred<<<1024, 256, 0, stream>>>(mempartB, bk, bv, ku_g, vu_g, rho, memT);
  k_emat<<<64, 512, 0, stream>>>(memT, Wqb, bq, Eb, qbAll);
  k_fmat<<<258, 512, 0, stream>>>(Eb, WoT, qbAll, bo, Fpart, c0acc);
  k_fred<<<128, 256, 0, stream>>>(Fpart, Fb);
  k_final2<<<64, 512, 0, stream>>>(Fb, xb, c0acc, out);
}

// Round 15
// 178.478 us; speedup vs baseline: 1.3795x; 1.0896x over previous
//
#include <hip/hip_runtime.h>

typedef __attribute__((ext_vector_type(8))) short bf16x8;
typedef __attribute__((ext_vector_type(4))) float f32x4;

#define DEV static __device__ __forceinline__

DEV unsigned short f2bf(float f){
  union { float f; unsigned u; } v; v.f = f;
  unsigned r = v.u + 0x7fffu + ((v.u >> 16) & 1u);
  return (unsigned short)(r >> 16);
}
DEV float bf2f(unsigned short u){
  union { unsigned u; float f; } v; v.u = ((unsigned)u) << 16;
  return v.f;
}
DEV unsigned long long pk4(float a, float b, float c, float d){
  unsigned lo = (unsigned)f2bf(a) | ((unsigned)f2bf(b) << 16);
  unsigned hi = (unsigned)f2bf(c) | ((unsigned)f2bf(d) << 16);
  return ((unsigned long long)hi << 32) | lo;
}

// =============== fused prep (64x64 tiles, full-line writes) ===============
__global__ __launch_bounds__(256) void k_prep(const float* __restrict__ x,
                                              const float* __restrict__ Wq,
                                              const float* __restrict__ Wr,
                                              const float* __restrict__ br,
                                              const float* __restrict__ Wk,
                                              const float* __restrict__ Wv,
                                              const float* __restrict__ Wo,
                                              const float* __restrict__ bias0,
                                              unsigned short* __restrict__ WkT,
                                              unsigned short* __restrict__ WvT,
                                              unsigned short* __restrict__ WoT,
                                              unsigned short* __restrict__ Wqb,
                                              unsigned short* __restrict__ xb,
                                              unsigned short* __restrict__ xT,
                                              float* __restrict__ routT){
  __shared__ float tile[64*65];          // 16.6 KB
  __shared__ float lg[32][8];
  __shared__ float rt2[32][8];
  int bid = blockIdx.x;
  int t = threadIdx.x;
  int tx = t & 63, ty = t >> 6;          // 64 x 4

  if (bid < 2048){                       // Wk (0..1023) / Wv (1024..2047): [8][256][2048] -> [8][2048][256]
    const float* src = (bid < 1024) ? Wk : Wv;
    unsigned short* dst = (bid < 1024) ? WkT : WvT;
    int q = bid & 1023;
    int bat = q >> 7, rem = q & 127;
    int c0 = (rem >> 2) * 64, r0 = (rem & 3) * 64;     // c0: hd(2048), r0: d(256)
    size_t boff = (size_t)bat * 256 * 2048;
    for (int i = 0; i < 16; i++)
      tile[(ty + i*4)*65 + tx] = src[boff + (size_t)(r0 + ty + i*4) * 2048 + c0 + tx];
    __syncthreads();
    for (int i = 0; i < 16; i++)
      dst[boff + (size_t)(c0 + ty + i*4) * 256 + r0 + tx] = f2bf(tile[tx*65 + ty + i*4]);
  } else if (bid < 2176){                // Wo: [2048][256] -> [256][2048]
    int q = bid - 2048;
    int r0 = (q >> 2) * 64, c0 = (q & 3) * 64;         // r0: 2048-dim, c0: 256-dim
    for (int i = 0; i < 16; i++)
      tile[(ty + i*4)*65 + tx] = Wo[(size_t)(r0 + ty + i*4) * 256 + c0 + tx];
    __syncthreads();
    for (int i = 0; i < 16; i++)
      WoT[(size_t)(c0 + ty + i*4) * 2048 + r0 + tx] = f2bf(tile[tx*65 + ty + i*4]);
  } else if (bid < 2432){                // Wq plain convert [256][2048]
    int q = bid - 2176;
    size_t idx = (size_t)q * 2048 + t * 8;
    f32x4 a = *(const f32x4*)(Wq + idx);
    f32x4 b = *(const f32x4*)(Wq + idx + 4);
    *(unsigned long long*)(Wqb + idx)     = pk4(a[0], a[1], a[2], a[3]);
    *(unsigned long long*)(Wqb + idx + 4) = pk4(b[0], b[1], b[2], b[3]);
  } else if (bid < 2688){                // x: [2][2048][256] -> xb + xT
    int q = bid - 2432;
    int bat = q >> 7, rem = q & 127;
    int r0 = (rem >> 2) * 64, c0 = (rem & 3) * 64;     // r0: s(2048), c0: d(256)
    size_t boff = (size_t)bat * 2048 * 256;
    for (int i = 0; i < 16; i++){
      float v = x[boff + (size_t)(r0 + ty + i*4) * 256 + c0 + tx];
      tile[(ty + i*4)*65 + tx] = v;
      xb[boff + (size_t)(r0 + ty + i*4) * 256 + c0 + tx] = f2bf(v);
    }
    __syncthreads();
    for (int i = 0; i < 16; i++)
      xT[(size_t)(bat*256 + c0 + ty + i*4) * 2048 + r0 + tx] = f2bf(tile[tx*65 + ty + i*4]);
  } else {                               // router: 128 blocks, 32 tokens each
    int row = t >> 3, mm = t & 7;
    int n = (bid - 2688) * 32 + row;
    const float* xr = x + (size_t)n * 256;
    float acc = 0.f;
    for (int d = 0; d < 256; d++) acc += xr[d] * Wr[d * 8 + mm];
    acc += br[mm];
    lg[row][mm] = acc;
    __syncthreads();
    if (t < 32){
      int r = t; int n2 = (bid - 2688) * 32 + r; int b = n2 >> 11;
      float mx = -1e30f;
      for (int i = 0; i < 8; i++) mx = fmaxf(mx, lg[r][i]);
      float s[8]; float sum = 0.f;
      for (int i = 0; i < 8; i++){ s[i] = __expf(lg[r][i] - mx); sum += s[i]; }
      for (int i = 0; i < 8; i++) s[i] /= sum;
      float bb[8];
      for (int i = 0; i < 8; i++) bb[i] = s[i] + bias0[b * 8 + i];
      int i1 = 0;
      for (int i = 1; i < 8; i++) if (bb[i] > bb[i1]) i1 = i;
      int i2 = -1;
      for (int i = 0; i < 8; i++){ if (i == i1) continue; if (i2 < 0 || bb[i] > bb[i2]) i2 = i; }
      float wsum = s[i1] + s[i2];
      for (int i = 0; i < 8; i++)
        rt2[r][i] = (i == i1) ? s[i1] / wsum : ((i == i2) ? s[i2] / wsum : 0.f);
    }
    __syncthreads();
    int n3 = (bid - 2688) * 32 + row;
    int b = n3 >> 11, sl = n3 & 2047;
    routT[((size_t)b * 8 + mm) * 2048 + sl] = rt2[row][mm];
  }
}

// =============== MERGED: gpart (bid<128) + usum (bid 128..255), 512 threads ===============
__global__ __launch_bounds__(512) void k_gusum(const unsigned short* __restrict__ xT,
                                               const unsigned short* __restrict__ xb,
                                               const float* __restrict__ routT,
                                               unsigned short* __restrict__ Gp,
                                               float* __restrict__ upart,
                                               float* __restrict__ rhop){
  __shared__ unsigned short As[256*72];
  __shared__ unsigned short Bs[256*72];
  __shared__ float rl[64];
  __shared__ float rl2[256];
  int bid = blockIdx.x;
  int t = threadIdx.x;
  if (bid >= 128){
    // ---- usum: 128 blocks = bm(16) x scq(8); 512 threads = 2 halves of 128-token chunks
    int bid2 = bid - 128;
    int scq = bid2 & 7, bm = bid2 >> 3, b = bm >> 3;
    int half = t >> 8, td = t & 255;
    if (t < 256) rl2[t] = routT[(size_t)bm * 2048 + scq * 256 + t];
    __syncthreads();
    float acc = 0.f;
    const unsigned short* xrow = xb + ((size_t)(b * 2048 + scq * 256 + half * 128)) * 256 + td;
    const float* rlh = rl2 + half * 128;
    for (int s = 0; s < 128; s++){
      float rv = rlh[s];
      if (rv != 0.f)
        acc += rv * bf2f(xrow[(size_t)s * 256]);
    }
    upart[(size_t)(bm*16 + scq*2 + half) * 256 + td] = acc;
    if (td == 0){
      float rs = 0.f;
      for (int s = 0; s < 128; s++) rs += rlh[s];
      rhop[bm*16 + scq*2 + half] = rs;
    }
    return;
  }
  // ---- gpart: 128 blocks = b(2) m(8) kc(8)
  int kc = bid & 7, m = (bid >> 3) & 7, b = bid >> 6;
  int bm = b * 8 + m;
  int lane = t & 63, w = t >> 6;
  int li = lane & 15, lgp = lane >> 4;
  int p = w >> 2, q = w & 3;
  f32x4 acc[8][4];
  for (int i = 0; i < 8; i++) for (int j = 0; j < 4; j++) acc[i][j] = (f32x4){0,0,0,0};
  for (int c4 = 0; c4 < 4; c4++){
    int s0 = kc * 256 + c4 * 64;
    if (t < 64) rl[t] = routT[(size_t)bm*2048 + s0 + t];
    __syncthreads();
    for (int qq = 0; qq < 4; qq++){
      int idx = t + qq*512;
      int row = idx >> 3, sc = (idx & 7) * 8;
      bf16x8 xv = *(const bf16x8*)(xT + ((size_t)(b*256 + row))*2048 + s0 + sc);
      *(bf16x8*)(&Bs[row*72 + sc]) = xv;
      f32x4 r0 = *(const f32x4*)(rl + sc);
      f32x4 r1 = *(const f32x4*)(rl + sc + 4);
      bf16x8 sv;
      sv[0]=(short)f2bf(bf2f((unsigned short)xv[0])*r0[0]);
      sv[1]=(short)f2bf(bf2f((unsigned short)xv[1])*r0[1]);
      sv[2]=(short)f2bf(bf2f((unsigned short)xv[2])*r0[2]);
      sv[3]=(short)f2bf(bf2f((unsigned short)xv[3])*r0[3]);
      sv[4]=(short)f2bf(bf2f((unsigned short)xv[4])*r1[0]);
      sv[5]=(short)f2bf(bf2f((unsigned short)xv[5])*r1[1]);
      sv[6]=(short)f2bf(bf2f((unsigned short)xv[6])*r1[2]);
      sv[7]=(short)f2bf(bf2f((unsigned short)xv[7])*r1[3]);
      *(bf16x8*)(&As[row*72 + sc]) = sv;
    }
    __syncthreads();
    for (int kk = 0; kk < 2; kk++){
      bf16x8 Bf[4];
      for (int j = 0; j < 4; j++)
        Bf[j] = *(const bf16x8*)(&Bs[(q*64 + j*16 + li)*72 + kk*32 + lgp*8]);
      for (int i = 0; i < 8; i++){
        bf16x8 Af = *(const bf16x8*)(&As[(p*128 + i*16 + li)*72 + kk*32 + lgp*8]);
        for (int j = 0; j < 4; j++)
          acc[i][j] = __builtin_amdgcn_mfma_f32_16x16x32_bf16(Af, Bf[j], acc[i][j], 0, 0, 0);
      }
    }
    __syncthreads();
  }
  unsigned short* Cs = As;                   // 64 x 264 overlay
  for (int ph = 0; ph < 4; ph++){
    if (q == ph){
      for (int i = 0; i < 8; i++)
        for (int j = 0; j < 4; j++){
          int rr = j*16 + li, cc = p*128 + i*16 + lgp*4;
          *(unsigned long long*)(&Cs[rr*264 + cc]) =
            pk4(acc[i][j][0], acc[i][j][1], acc[i][j][2], acc[i][j][3]);
        }
    }
    __syncthreads();
    for (int qq = 0; qq < 4; qq++){
      int idx = t + qq*512;
      int row = idx >> 5, cc = (idx & 31) * 8;
      *(bf16x8*)(Gp + (((size_t)bm*8 + kc) << 16) + (size_t)(ph*64 + row)*256 + cc) =
        *(const bf16x8*)(&Cs[row*264 + cc]);
    }
    __syncthreads();
  }
}

// =============== MERGED: gred (bid<512) + bias (bid 512..639), 256 threads ===============
__global__ __launch_bounds__(256) void k_gbias(const unsigned short* __restrict__ Gp,
                                               const unsigned short* __restrict__ WkT,
                                               const unsigned short* __restrict__ WvT,
                                               const float* __restrict__ upart,
                                               const float* __restrict__ rhop,
                                               unsigned short* __restrict__ G,
                                               float* __restrict__ ku_g,
                                               float* __restrict__ vu_g,
                                               float* __restrict__ rho){
  __shared__ float uL[256];
  int bid = blockIdx.x;
  int t = threadIdx.x;
  if (bid < 512){
    // ---- gred
    int idx = bid * 256 + t;
    int bm = idx >> 13; size_t e8 = (size_t)(idx & 8191) * 8;
    float s[8] = {0,0,0,0,0,0,0,0};
    for (int kc = 0; kc < 8; kc++){
      bf16x8 v = *(const bf16x8*)(Gp + (((size_t)bm*8 + kc) << 16) + e8);
      for (int j = 0; j < 8; j++) s[j] += bf2f((unsigned short)v[j]);
    }
    *(unsigned long long*)(G + ((size_t)bm << 16) + e8)     = pk4(s[0], s[1], s[2], s[3]);
    *(unsigned long long*)(G + ((size_t)bm << 16) + e8 + 4) = pk4(s[4], s[5], s[6], s[7]);
    return;
  }
  // ---- bias: 128 blocks
  int bid2 = bid - 512;
  int bm = bid2 >> 3, hseg = bid2 & 7, m = bm & 7;
  {
    float s = 0.f;
    for (int scn = 0; scn < 16; scn++)
      s += upart[(size_t)(bm*16 + scn) * 256 + t];
    uL[t] = s;
  }
  if (hseg == 0 && t == 0){
    float rs = 0.f;
    for (int scn = 0; scn < 16; scn++) rs += rhop[bm*16 + scn];
    rho[bm] = rs;
  }
  __syncthreads();
  int hd = hseg * 256 + t;
  const unsigned short* wk = WkT + ((size_t)m*2048 + hd) * 256;
  const unsigned short* wv = WvT + ((size_t)m*2048 + hd) * 256;
  float sk = 0.f, sv = 0.f;
  for (int d8 = 0; d8 < 256; d8 += 8){
    bf16x8 a = *(const bf16x8*)(wk + d8);
    bf16x8 c = *(const bf16x8*)(wv + d8);
    for (int j = 0; j < 8; j++){
      sk += bf2f((unsigned short)a[j]) * uL[d8+j];
      sv += bf2f((unsigned short)c[j]) * uL[d8+j];
    }
  }
  ku_g[(size_t)bm*2048 + hd] = sk;
  vu_g[(size_t)bm*2048 + hd] = sv;
}

// =============== Tt[bm][vd(hd) 2048][d1 256] = (G[bm] @ Wv_m)^T ===============
__global__ __launch_bounds__(512) void k_tmat(const unsigned short* __restrict__ G,
                                              const unsigned short* __restrict__ WvT,
                                              unsigned short* __restrict__ Tt){
  __shared__ unsigned short Cs[64*264];
  int bid = blockIdx.x;                         // 256 = bm(16) * hseg(16)
  int hseg = bid & 15, bm = bid >> 4, m = bm & 7;
  int t = threadIdx.x, lane = t & 63, w = t >> 6;
  int li = lane & 15, lgp = lane >> 4;
  int r = w >> 1, c = w & 1;
  f32x4 acc[4][4];
  for (int i = 0; i < 4; i++) for (int j = 0; j < 4; j++) acc[i][j] = (f32x4){0,0,0,0};
  const unsigned short* gp = G + ((size_t)bm << 16) + (size_t)(r*64 + li)*256 + lgp*8;
  const unsigned short* wp = WvT + ((size_t)m*2048 + hseg*128 + c*64 + li)*256 + lgp*8;
  #pragma unroll
  for (int kk = 0; kk < 8; kk++){
    bf16x8 Bf[4];
    for (int j = 0; j < 4; j++)
      Bf[j] = *(const bf16x8*)(wp + (size_t)(j*16)*256 + kk*32);
    for (int i = 0; i < 4; i++){
      bf16x8 Af = *(const bf16x8*)(gp + (size_t)(i*16)*256 + kk*32);
      for (int j = 0; j < 4; j++)
        acc[i][j] = __builtin_amdgcn_mfma_f32_16x16x32_bf16(Af, Bf[j], acc[i][j], 0, 0, 0);
    }
  }
  for (int ph = 0; ph < 2; ph++){
    if (c == ph){
      for (int i = 0; i < 4; i++)
        for (int j = 0; j < 4; j++)
          *(unsigned long long*)(&Cs[(j*16 + li)*264 + r*64 + i*16 + lgp*4]) =
            pk4(acc[i][j][0], acc[i][j][1], acc[i][j][2], acc[i][j][3]);
    }
    __syncthreads();
    for (int q = 0; q < 4; q++){
      int idx = t + q*512;
      int row = idx >> 5, cc = (idx & 31) * 8;
      *(bf16x8*)(Tt + ((size_t)bm*2048 + hseg*128 + ph*64 + row)*256 + cc) =
        *(const bf16x8*)(&Cs[row*264 + cc]);
    }
    __syncthreads();
  }
}

// =============== mempartB[m][h][vq][kq][b] (128x128 bf16) = Tt_m x WkT_m (both b per block) ===============
__global__ __launch_bounds__(512) void k_kmat3(const unsigned short* __restrict__ Tt,
                                               const unsigned short* __restrict__ WkT,
                                               unsigned short* __restrict__ mempartB){
  int bid = blockIdx.x;                         // 256 = h(8) vq(2) kq(2) m(8)
  int m = bid & 7, kq = (bid >> 3) & 1, vq = (bid >> 4) & 1, h = bid >> 5;
  int hd0 = h * 256;
  int t = threadIdx.x, lane = t & 63, w = t >> 6;
  int li = lane & 15, lgp = lane >> 4;
  int wr = w >> 2, wc = w & 3;                  // vd 2x64-blk, kd 4x32-blk
  f32x4 acc[2][2][4];                           // [b][i: kd16][j: vd16]
  for (int b = 0; b < 2; b++)
    for (int i = 0; i < 2; i++)
      for (int j = 0; j < 4; j++) acc[b][i][j] = (f32x4){0,0,0,0};
  const unsigned short* ap  = WkT + ((size_t)m*2048 + hd0 + kq*128 + wc*32 + li)*256 + lgp*8;
  const unsigned short* bp0 = Tt + ((size_t)(m)*2048 + hd0 + vq*128 + wr*64 + li)*256 + lgp*8;
  const unsigned short* bp1 = Tt + ((size_t)(8 + m)*2048 + hd0 + vq*128 + wr*64 + li)*256 + lgp*8;
  #pragma unroll
  for (int kk = 0; kk < 8; kk++){
    bf16x8 Af[2], B0[4], B1[4];
    Af[0] = *(const bf16x8*)(ap + kk*32);
    Af[1] = *(const bf16x8*)(ap + 16*256 + kk*32);
    for (int j = 0; j < 4; j++){
      B0[j] = *(const bf16x8*)(bp0 + (size_t)(j*16)*256 + kk*32);
      B1[j] = *(const bf16x8*)(bp1 + (size_t)(j*16)*256 + kk*32);
    }
    for (int i = 0; i < 2; i++)
      for (int j = 0; j < 4; j++){
        acc[0][i][j] = __builtin_amdgcn_mfma_f32_16x16x32_bf16(Af[i], B0[j], acc[0][i][j], 0, 0, 0);
        acc[1][i][j] = __builtin_amdgcn_mfma_f32_16x16x32_bf16(Af[i], B1[j], acc[1][i][j], 0, 0, 0);
      }
  }
  for (int b = 0; b < 2; b++){
    unsigned short* Fp = mempartB + ((((((size_t)m*8 + h)*2 + vq)*2 + kq)*2 + b)) * 16384;
    for (int j = 0; j < 4; j++){
      int vdt = wr*64 + j*16 + li;
      for (int i = 0; i < 2; i++){
        int kdt = wc*32 + i*16 + lgp*4;
        *(unsigned long long*)(Fp + (size_t)vdt*128 + kdt) =
          pk4(acc[b][i][j][0], acc[b][i][j][1], acc[b][i][j][2], acc[b][i][j][3]);
      }
    }
  }
}

// =============== k_kred: memT[bh][vd][kd] = Sum_m mempartB + rank-1 epilogue ===============
__global__ __launch_bounds__(256) void k_kred(const unsigned short* __restrict__ mempartB,
                                              const float* __restrict__ bk,
                                              const float* __restrict__ bv,
                                              const float* __restrict__ ku_g,
                                              const float* __restrict__ vu_g,
                                              const float* __restrict__ rho,
                                              unsigned short* __restrict__ memT){
  int idx = blockIdx.x * 256 + threadIdx.x;     // 262144 = 16bh x 256vd x 64(kd/4)
  int bh = idx >> 14;
  int rem = idx & 16383;
  int vd = rem >> 6, kd = (rem & 63) * 4;
  int b = bh >> 3, h = bh & 7;
  int vdg = h*256 + vd, kdg = h*256 + kd;
  int vq = vd >> 7, kq = kd >> 7;
  size_t src = ((((size_t)h*2 + vq)*2 + kq)*2 + b) * 16384 + (size_t)(vd & 127)*128 + (kd & 127);
  f32x4 s = (f32x4){0,0,0,0};
  #pragma unroll
  for (int m = 0; m < 8; m++){
    unsigned long long v = *(const unsigned long long*)(mempartB + (size_t)m*1048576 + src);
    s[0] += bf2f((unsigned short)v);
    s[1] += bf2f((unsigned short)(v >> 16));
    s[2] += bf2f((unsigned short)(v >> 32));
    s[3] += bf2f((unsigned short)(v >> 48));
  }
  #pragma unroll
  for (int m = 0; m < 8; m++){
    float bvv = bv[(size_t)m*2048 + vdg];
    float bb  = vu_g[(size_t)(b*8+m)*2048 + vdg] + rho[b*8+m]*bvv;
    f32x4 ku4 = *(const f32x4*)(ku_g + (size_t)(b*8+m)*2048 + kdg);
    f32x4 bk4 = *(const f32x4*)(bk + (size_t)m*2048 + kdg);
    s[0] += ku4[0]*bvv + bk4[0]*bb;
    s[1] += ku4[1]*bvv + bk4[1]*bb;
    s[2] += ku4[2]*bvv + bk4[2]*bb;
    s[3] += ku4[3]*bvv + bk4[3]*bb;
  }
  *(unsigned long long*)(memT + (size_t)bh*65536 + (size_t)vd*256 + kd) =
    pk4(s[0], s[1], s[2], s[3]);
}

// =============== E_h = Wq_h @ mem_h -> Eb; qbAll = bq_h . mem_h ===============
__global__ __launch_bounds__(512) void k_emat(const unsigned short* __restrict__ memT,
                                              const unsigned short* __restrict__ Wqb,
                                              const float* __restrict__ bq,
                                              unsigned short* __restrict__ Eb,
                                              float* __restrict__ qbAll){
  __shared__ unsigned short Cs[16*264];
  int bid = blockIdx.x;                        // 64 = bh(16) * dseg(4)
  int dseg = bid & 3, bh = bid >> 2;
  int b = bh >> 3, h = bh & 7;
  int hd0 = h * 256, d0 = dseg * 64;
  int t = threadIdx.x, lane = t & 63, w = t >> 6;
  int li = lane & 15, lgp = lane >> 4;
  int r = w >> 2, c = w & 3;
  f32x4 acc[8];
  for (int i = 0; i < 8; i++) acc[i] = (f32x4){0,0,0,0};
  for (int kk = 0; kk < 8; kk++){
    bf16x8 Bf = *(const bf16x8*)(Wqb + (size_t)(d0 + c*16 + li)*2048 + hd0 + kk*32 + lgp*8);
    for (int i = 0; i < 8; i++){
      bf16x8 Af = *(const bf16x8*)(memT + (size_t)bh*65536 + (size_t)(r*128 + i*16 + li)*256 + kk*32 + lgp*8);
      acc[i] = __builtin_amdgcn_mfma_f32_16x16x32_bf16(Af, Bf, acc[i], 0, 0, 0);
    }
  }
  if (dseg == 0 && t < 256){
    const unsigned short* mrow = memT + (size_t)bh*65536 + (size_t)t*256;
    float s = 0.f;
    for (int k8 = 0; k8 < 256; k8 += 8){
      bf16x8 v = *(const bf16x8*)(mrow + k8);
      for (int e = 0; e < 8; e++) s += bf2f((unsigned short)v[e]) * bq[hd0 + k8 + e];
    }
    qbAll[(size_t)b*2048 + hd0 + t] = s;
  }
  for (int ph = 0; ph < 4; ph++){
    if (c == ph){
      for (int i = 0; i < 8; i++)
        *(unsigned long long*)(&Cs[li*264 + r*128 + i*16 + lgp*4]) =
          pk4(acc[i][0], acc[i][1], acc[i][2], acc[i][3]);
    }
    __syncthreads();
    {
      int row = t >> 5, cc = (t & 31) * 8;
      *(bf16x8*)(Eb + (size_t)b*524288 + (size_t)(d0 + ph*16 + row)*2048 + hd0 + cc) =
        *(const bf16x8*)(&Cs[row*264 + cc]);
    }
    __syncthreads();
  }
}

// =============== Fpart = Eb x Wo slice-K (split-K 8); tail: c0 ===============
__global__ __launch_bounds__(512) void k_fmat(const unsigned short* __restrict__ Eb,
                                              const unsigned short* __restrict__ WoT,
                                              const float* __restrict__ qbAll,
                                              const float* __restrict__ bo,
                                              float* __restrict__ Fpart,
                                              float* __restrict__ c0acc){
  __shared__ float qL[2048];
  int bid = blockIdx.x;
  int t = threadIdx.x;
  if (bid >= 256){
    int b = bid - 256;
    for (int i = t; i < 2048; i += 512) qL[i] = qbAll[(size_t)b * 2048 + i];
    __syncthreads();
    int w = t >> 6, lane = t & 63;
    for (int dd = w; dd < 256; dd += 8){
      const unsigned short* wrow = WoT + (size_t)dd * 2048 + lane * 8;
      const float* qp = qL + lane * 8;
      float s = 0.f;
      for (int pass = 0; pass < 4; pass++){
        bf16x8 v = *(const bf16x8*)(wrow + pass * 512);
        const float* q = qp + pass * 512;
        for (int e = 0; e < 8; e++) s += bf2f((unsigned short)v[e]) * q[e];
      }
      for (int off = 32; off; off >>= 1) s += __shfl_down(s, off);
      if (lane == 0) c0acc[(size_t)b * 256 + dd] = s + bo[dd];
    }
    return;
  }
  int ks = bid & 7, dseg = (bid >> 3) & 3, doseg = (bid >> 5) & 3, b = bid >> 7;
  int do0 = doseg * 64, d0 = dseg * 64, k0 = ks * 256;
  int lane = t & 63, w = t >> 6;
  int li = lane & 15, lgp = lane >> 4;
  int r = w >> 2, c = w & 3;
  f32x4 acc[2];
  acc[0] = (f32x4){0,0,0,0}; acc[1] = (f32x4){0,0,0,0};
  const unsigned short* bp = Eb + (size_t)b*524288 + (size_t)(d0 + c*16 + li)*2048 + k0 + lgp*8;
  const unsigned short* ap = WoT + (size_t)(do0 + r*32 + li)*2048 + k0 + lgp*8;
  #pragma unroll
  for (int kk = 0; kk < 8; kk++){
    bf16x8 Bf = *(const bf16x8*)(bp + kk*32);
    bf16x8 Af0 = *(const bf16x8*)(ap + kk*32);
    bf16x8 Af1 = *(const bf16x8*)(ap + kk*32 + 16*2048);
    acc[0] = __builtin_amdgcn_mfma_f32_16x16x32_bf16(Af0, Bf, acc[0], 0, 0, 0);
    acc[1] = __builtin_amdgcn_mfma_f32_16x16x32_bf16(Af1, Bf, acc[1], 0, 0, 0);
  }
  int dd = d0 + c*16 + li;
  float* Fp = Fpart + ((size_t)(ks*2 + b)) * 65536;
  for (int i = 0; i < 2; i++){
    int dor = do0 + r*32 + i*16 + lgp*4;
    float* p = Fp + (size_t)dor*256 + dd;
    p[0]   = acc[i][0];
    p[256] = acc[i][1];
    p[512] = acc[i][2];
    p[768] = acc[i][3];
  }
}

// =============== reduce Fpart over ks -> Fb ===============
__global__ __launch_bounds__(256) void k_fred(const float* __restrict__ Fpart,
                                              unsigned short* __restrict__ Fb){
  int idx = blockIdx.x * 256 + threadIdx.x;
  int b = idx >> 14; int e4 = (idx & 16383) * 4;
  f32x4 s = (f32x4){0,0,0,0};
  for (int ks = 0; ks < 8; ks++){
    f32x4 v = *(const f32x4*)(Fpart + ((size_t)(ks*2 + b)) * 65536 + e4);
    s[0] += v[0]; s[1] += v[1]; s[2] += v[2]; s[3] += v[3];
  }
  *(unsigned long long*)(Fb + (size_t)b*65536 + e4) = pk4(s[0], s[1], s[2], s[3]);
}

// =============== out[tok][do] = x @ F(bf16) + c0 ===============
__global__ __launch_bounds__(512) void k_final2(const unsigned short* __restrict__ Fb,
                                                const unsigned short* __restrict__ xb,
                                                const float* __restrict__ c0acc,
                                                float* __restrict__ out){
  int bid = blockIdx.x;                        // 64 = b(2) * tc(32)
  int tc = bid & 31, b = bid >> 5;
  int t = threadIdx.x, lane = t & 63, w = t >> 6;
  int li = lane & 15, lgp = lane >> 4;
  int r = w >> 1, c = w & 1;
  int tok0 = b * 2048 + tc * 64;
  f32x4 acc[4][2];
  for (int i = 0; i < 4; i++) for (int j = 0; j < 2; j++) acc[i][j] = (f32x4){0,0,0,0};
  for (int kk = 0; kk < 8; kk++){
    bf16x8 Bf[2];
    for (int j = 0; j < 2; j++)
      Bf[j] = *(const bf16x8*)(xb + (size_t)(tok0 + c*32 + j*16 + li)*256 + kk*32 + lgp*8);
    for (int i = 0; i < 4; i++){
      bf16x8 af = *(const bf16x8*)(Fb + (size_t)b*65536 + (size_t)(r*64 + i*16 + li)*256 + kk*32 + lgp*8);
      for (int j = 0; j < 2; j++)
        acc[i][j] = __builtin_amdgcn_mfma_f32_16x16x32_bf16(af, Bf[j], acc[i][j], 0, 0, 0);
    }
  }
  for (int i = 0; i < 4; i++){
    int dol = r*64 + i*16 + lgp*4;
    f32x4 c4 = *(const f32x4*)(c0acc + (size_t)b*256 + dol);
    for (int j = 0; j < 2; j++){
      int tokl = c*32 + j*16 + li;
      f32x4 v = acc[i][j];
      v[0] += c4[0]; v[1] += c4[1]; v[2] += c4[2]; v[3] += c4[3];
      *(f32x4*)(out + (size_t)(tok0 + tokl)*256 + dol) = v;
    }
  }
}

extern "C" void kernel_launch(void* const* d_in, const int* in_sizes, int n_in,
                              void* d_out, int out_size, void* d_ws, size_t ws_size,
                              hipStream_t stream) {
  const float* x     = (const float*)d_in[0];
  const float* Wq    = (const float*)d_in[1];
  const float* bq    = (const float*)d_in[2];
  const float* Wr    = (const float*)d_in[3];
  const float* br    = (const float*)d_in[4];
  const float* Wk    = (const float*)d_in[5];
  const float* bk    = (const float*)d_in[6];
  const float* Wv    = (const float*)d_in[7];
  const float* bv    = (const float*)d_in[8];
  const float* Wo    = (const float*)d_in[9];
  const float* bo    = (const float*)d_in[10];
  const float* bias0 = (const float*)d_in[11];
  float* out = (float*)d_out;

  char* ws = (char*)d_ws;
  size_t off = 0;
  auto alloc = [&](size_t bytes) -> char* {
    char* p = ws + off;
    off = (off + bytes + 255) & ~(size_t)255;
    return p;
  };
  unsigned short* xb   = (unsigned short*)alloc((size_t)4096 * 256 * 2);      // 2 MB
  unsigned short* xT   = (unsigned short*)alloc((size_t)2 * 256 * 2048 * 2);  // 2 MB
  unsigned short* Wqb  = (unsigned short*)alloc((size_t)256 * 2048 * 2);      // 1 MB
  unsigned short* WkT  = (unsigned short*)alloc((size_t)8 * 2048 * 256 * 2);  // 8 MB
  unsigned short* WvT  = (unsigned short*)alloc((size_t)8 * 2048 * 256 * 2);  // 8 MB
  unsigned short* WoT  = (unsigned short*)alloc((size_t)256 * 2048 * 2);      // 1 MB
  float*          routT= (float*)alloc((size_t)16 * 2048 * 4);                // 128 KB
  float*          upart= (float*)alloc((size_t)256 * 256 * 4);                // 256 KB
  float*          rhop = (float*)alloc((size_t)256 * 4);
  float*          rho  = (float*)alloc((size_t)16 * 4);
  float*          ku_g = (float*)alloc((size_t)16 * 2048 * 4);
  float*          vu_g = (float*)alloc((size_t)16 * 2048 * 4);
  unsigned short* Gp   = (unsigned short*)alloc((size_t)16 * 8 * 65536 * 2);  // 16 MB
  unsigned short* G    = (unsigned short*)alloc((size_t)16 * 65536 * 2);      // 2 MB
  unsigned short* memT = (unsigned short*)alloc((size_t)16 * 65536 * 2);      // 2 MB
  unsigned short* Eb   = (unsigned short*)alloc((size_t)2 * 256 * 2048 * 2);  // 2 MB
  float*          qbAll= (float*)alloc((size_t)2 * 2048 * 4);
  float*          Fpart= (float*)alloc((size_t)16 * 65536 * 4);               // 4 MB
  unsigned short* Fb   = (unsigned short*)alloc((size_t)2 * 65536 * 2);       // 256 KB
  float*          c0acc= (float*)alloc((size_t)2 * 256 * 4);
  unsigned short* mempartB = (unsigned short*)alloc((size_t)8 * 1048576 * 2); // 16 MB
  unsigned short* Tt   = Gp;      // alias: Gp dead after k_gbias(gred part)
  (void)ws_size; (void)in_sizes; (void)n_in; (void)out_size;

  k_prep<<<2816, 256, 0, stream>>>(x, Wq, Wr, br, Wk, Wv, Wo, bias0,
                                   WkT, WvT, WoT, Wqb, xb, xT, routT);
  k_gusum<<<256, 512, 0, stream>>>(xT, xb, routT, Gp, upart, rhop);
  k_gbias<<<640, 256, 0, stream>>>(Gp, WkT, WvT, upart, rhop, G, ku_g, vu_g, rho);
  k_tmat<<<256, 512, 0, stream>>>(G, WvT, Tt);
  k_kmat3<<<256, 512, 0, stream>>>(Tt, WkT, mempartB);
  k_kred<<<1024, 256, 0, stream>>>(mempartB, bk, bv, ku_g, vu_g, rho, memT);
  k_emat<<<64, 512, 0, stream>>>(memT, Wqb, bq, Eb, qbAll);
  k_fmat<<<258, 512, 0, stream>>>(Eb, WoT, qbAll, bo, Fpart, c0acc);
  k_fred<<<128, 256, 0, stream>>>(Fpart, Fb);
  k_final2<<<64, 512, 0, stream>>>(Fb, xb, c0acc, out);
}